// Round 1
// baseline (1769.753 us; speedup 1.0000x reference)
//
#include <hip/hip_runtime.h>
#include <hip/hip_bf16.h>

// ---------------- graph build ----------------

__global__ __launch_bounds__(256) void init_deg_kernel(unsigned int* __restrict__ deg, int n) {
    int i = blockIdx.x * 256 + threadIdx.x;
    if (i < n) deg[i] = 1u;  // self-loop
}

__global__ __launch_bounds__(256) void count_edges_kernel(const int* __restrict__ col,
                                                          unsigned int* __restrict__ deg, int E) {
    int e = blockIdx.x * 256 + threadIdx.x;
    if (e < E) atomicAdd(&deg[col[e]], 1u);
}

__global__ __launch_bounds__(256) void dinv_kernel(const unsigned int* __restrict__ deg,
                                                   float* __restrict__ dinv, int n) {
    int i = blockIdx.x * 256 + threadIdx.x;
    if (i < n) dinv[i] = 1.0f / sqrtf((float)deg[i]);
}

// single-block exclusive scan of deg -> offs (N+1) and cursor copy
__global__ __launch_bounds__(1024) void scan_kernel(const unsigned int* __restrict__ deg,
                                                    int* __restrict__ offs,
                                                    int* __restrict__ cursor, int n) {
    __shared__ int sums[1024];
    const int t = threadIdx.x;
    const int CH = (n + 1023) / 1024;
    int base = t * CH;
    int lim = base + CH; if (lim > n) lim = n;
    int s = 0;
    for (int i = base; i < lim; ++i) s += (int)deg[i];
    sums[t] = s;
    __syncthreads();
    // Hillis-Steele inclusive scan
    for (int off = 1; off < 1024; off <<= 1) {
        int v = (t >= off) ? sums[t - off] : 0;
        __syncthreads();
        sums[t] += v;
        __syncthreads();
    }
    int run = (t == 0) ? 0 : sums[t - 1];
    for (int i = base; i < lim; ++i) {
        offs[i] = run;
        cursor[i] = run;
        run += (int)deg[i];
    }
    if (t == 1023) offs[n] = sums[1023];
}

__global__ __launch_bounds__(256) void fill_csr_kernel(const int* __restrict__ row,
                                                       const int* __restrict__ col,
                                                       const float* __restrict__ dinv,
                                                       int* __restrict__ cursor,
                                                       int* __restrict__ crow,
                                                       float* __restrict__ cw,
                                                       int E, int n) {
    int t = blockIdx.x * 256 + threadIdx.x;
    if (t < E) {
        int r = row[t], c = col[t];
        int pos = atomicAdd(&cursor[c], 1);
        crow[pos] = r;
        cw[pos] = dinv[r] * dinv[c];
    } else if (t < E + n) {
        int i = t - E;
        int pos = atomicAdd(&cursor[i], 1);
        crow[pos] = i;
        float d = dinv[i];
        cw[pos] = d * d;
    }
}

// ---------------- propagation: one wave per node ----------------

__global__ __launch_bounds__(256) void hop_kernel(const int* __restrict__ offs,
                                                  const int* __restrict__ rows,
                                                  const float* __restrict__ wts,
                                                  const float* __restrict__ xin,
                                                  float* __restrict__ xout, int n) {
    int wave = (blockIdx.x * 256 + threadIdx.x) >> 6;
    wave = __builtin_amdgcn_readfirstlane(wave);  // wave-uniform node id -> scalar loads
    if (wave >= n) return;
    const int lane = threadIdx.x & 63;
    const int beg = offs[wave];
    const int end = offs[wave + 1];
    const float2* __restrict__ x2 = (const float2*)xin;
    float ax = 0.f, ay = 0.f;
    int e = beg;
    for (; e + 2 <= end; e += 2) {
        int r0 = rows[e], r1 = rows[e + 1];
        float w0 = wts[e], w1 = wts[e + 1];
        float2 v0 = x2[(size_t)r0 * 64 + lane];
        float2 v1 = x2[(size_t)r1 * 64 + lane];
        ax = fmaf(w0, v0.x, ax); ay = fmaf(w0, v0.y, ay);
        ax = fmaf(w1, v1.x, ax); ay = fmaf(w1, v1.y, ay);
    }
    if (e < end) {
        int r = rows[e];
        float w = wts[e];
        float2 v = x2[(size_t)r * 64 + lane];
        ax = fmaf(w, v.x, ax); ay = fmaf(w, v.y, ay);
    }
    float2 o; o.x = ax; o.y = ay;
    ((float2*)xout)[(size_t)wave * 64 + lane] = o;
}

// ---------------- output ----------------

__global__ __launch_bounds__(256) void init_out_kernel(float* __restrict__ out,
                                                       const float* __restrict__ b, int total) {
    int t = blockIdx.x * 256 + threadIdx.x;
    if (t < total) out[t] = b[t & 127];
}

// C[n,128] += A[n,128] @ B[128,128]; 64-row tile per block, 256 threads,
// each thread: 8 rows x 4 cols.
__global__ __launch_bounds__(256) void gemm_acc_kernel(const float* __restrict__ A,
                                                       const float* __restrict__ B,
                                                       float* __restrict__ C, int n) {
    __shared__ float As[64][32];
    __shared__ float Bs[32][128];
    const int tid = threadIdx.x;
    const int bm = blockIdx.x * 64;
    const int tc = tid & 31;   // col group: cols 4*tc .. 4*tc+3
    const int tr = tid >> 5;   // row group: rows tr*8 .. tr*8+7

    float acc[8][4];
#pragma unroll
    for (int i = 0; i < 8; ++i)
#pragma unroll
        for (int c = 0; c < 4; ++c) acc[i][c] = 0.f;

    const int r0 = tid >> 2;          // 0..63
    const int c0 = (tid & 3) * 8;     // 0,8,16,24
    int arow = bm + r0;
    if (arow > n - 1) arow = n - 1;   // clamp: safe read, result discarded

    for (int jt = 0; jt < 128; jt += 32) {
        const float* src = A + (size_t)arow * 128 + jt + c0;
        float4 a0 = *(const float4*)(src);
        float4 a1 = *(const float4*)(src + 4);
        *(float4*)&As[r0][c0]     = a0;
        *(float4*)&As[r0][c0 + 4] = a1;
        const float4* bsrc = (const float4*)(B + jt * 128);
        float4* bdst = (float4*)Bs;
#pragma unroll
        for (int q = 0; q < 4; ++q) bdst[tid + q * 256] = bsrc[tid + q * 256];
        __syncthreads();
#pragma unroll
        for (int j4 = 0; j4 < 32; j4 += 4) {
            float4 w0 = *(const float4*)&Bs[j4 + 0][tc * 4];
            float4 w1 = *(const float4*)&Bs[j4 + 1][tc * 4];
            float4 w2 = *(const float4*)&Bs[j4 + 2][tc * 4];
            float4 w3 = *(const float4*)&Bs[j4 + 3][tc * 4];
#pragma unroll
            for (int i = 0; i < 8; ++i) {
                float4 av = *(const float4*)&As[tr * 8 + i][j4];
                acc[i][0] += av.x * w0.x + av.y * w1.x + av.z * w2.x + av.w * w3.x;
                acc[i][1] += av.x * w0.y + av.y * w1.y + av.z * w2.y + av.w * w3.y;
                acc[i][2] += av.x * w0.z + av.y * w1.z + av.z * w2.z + av.w * w3.z;
                acc[i][3] += av.x * w0.w + av.y * w1.w + av.z * w2.w + av.w * w3.w;
            }
        }
        __syncthreads();
    }
#pragma unroll
    for (int i = 0; i < 8; ++i) {
        int row = bm + tr * 8 + i;
        if (row < n) {
            float4* cp = (float4*)(C + (size_t)row * 128 + tc * 4);
            float4 cv = *cp;
            cv.x += acc[i][0]; cv.y += acc[i][1]; cv.z += acc[i][2]; cv.w += acc[i][3];
            *cp = cv;
        }
    }
}

// ---------------- launch ----------------

extern "C" void kernel_launch(void* const* d_in, const int* in_sizes, int n_in,
                              void* d_out, int out_size, void* d_ws, size_t ws_size,
                              hipStream_t stream) {
    const int D = 128;
    const int N = in_sizes[0] / D;
    const int E = in_sizes[1] / 2;
    const int K = 8;

    const float* feature = (const float*)d_in[0];
    const int*   ei      = (const int*)d_in[1];
    const float* W       = (const float*)d_in[2];
    const float* bvec    = (const float*)d_in[3];
    float* out = (float*)d_out;

    const int* row = ei;
    const int* col = ei + E;

    // workspace carve-up (256B aligned regions)
    char* p = (char*)d_ws;
    auto alloc = [&](size_t bytes) {
        char* r = p;
        p += (bytes + 255) & ~(size_t)255;
        return r;
    };
    unsigned int* deg = (unsigned int*)alloc((size_t)N * 4);
    float* dinv       = (float*)alloc((size_t)N * 4);
    int* offs         = (int*)alloc((size_t)(N + 1) * 4);
    int* cursor       = (int*)alloc((size_t)N * 4);
    int* crow         = (int*)alloc((size_t)(E + N) * 4);
    float* cw         = (float*)alloc((size_t)(E + N) * 4);
    float* xA         = (float*)alloc((size_t)N * D * 4);
    float* xB         = (float*)alloc((size_t)N * D * 4);

    init_deg_kernel<<<(N + 255) / 256, 256, 0, stream>>>(deg, N);
    count_edges_kernel<<<(E + 255) / 256, 256, 0, stream>>>(col, deg, E);
    dinv_kernel<<<(N + 255) / 256, 256, 0, stream>>>(deg, dinv, N);
    scan_kernel<<<1, 1024, 0, stream>>>(deg, offs, cursor, N);
    fill_csr_kernel<<<(E + N + 255) / 256, 256, 0, stream>>>(row, col, dinv, cursor, crow, cw, E, N);

    init_out_kernel<<<(N * D + 255) / 256, 256, 0, stream>>>(out, bvec, N * D);

    // hop 0 contribution: feature @ W[0:128]
    gemm_acc_kernel<<<(N + 63) / 64, 256, 0, stream>>>(feature, W, out, N);

    const float* xin = feature;
    float* xout = xA;
    for (int k = 1; k <= K; ++k) {
        hop_kernel<<<(N * 64 + 255) / 256, 256, 0, stream>>>(offs, crow, cw, xin, xout, N);
        gemm_acc_kernel<<<(N + 63) / 64, 256, 0, stream>>>(xout, W + (size_t)k * D * D, out, N);
        xin = xout;
        xout = (xout == xA) ? xB : xA;
    }
}

// Round 5
// 1609.515 us; speedup vs baseline: 1.0996x; 1.0996x over previous
//
#include <hip/hip_runtime.h>
#include <hip/hip_bf16.h>

// ---------------- graph build ----------------

__global__ __launch_bounds__(256) void init_deg_kernel(unsigned int* __restrict__ deg, int n) {
    int i = blockIdx.x * 256 + threadIdx.x;
    if (i < n) deg[i] = 1u;  // self-loop
}

__global__ __launch_bounds__(256) void count_edges_kernel(const int* __restrict__ col,
                                                          unsigned int* __restrict__ deg, int E) {
    int e = blockIdx.x * 256 + threadIdx.x;
    if (e < E) atomicAdd(&deg[col[e]], 1u);
}

__global__ __launch_bounds__(256) void dinv_kernel(const unsigned int* __restrict__ deg,
                                                   float* __restrict__ dinv, int n) {
    int i = blockIdx.x * 256 + threadIdx.x;
    if (i < n) dinv[i] = 1.0f / sqrtf((float)deg[i]);
}

// ---- parallel 3-phase exclusive scan of deg -> offs/cursor ----

__global__ __launch_bounds__(256) void block_sum_kernel(const unsigned int* __restrict__ deg,
                                                        int* __restrict__ bsum, int n) {
    __shared__ int sm[256];
    int i = blockIdx.x * 256 + threadIdx.x;
    sm[threadIdx.x] = (i < n) ? (int)deg[i] : 0;
    __syncthreads();
    for (int off = 128; off > 0; off >>= 1) {
        if (threadIdx.x < off) sm[threadIdx.x] += sm[threadIdx.x + off];
        __syncthreads();
    }
    if (threadIdx.x == 0) bsum[blockIdx.x] = sm[0];
}

// single block: exclusive scan of nb (<=1024) block sums; writes total to offs[n]
__global__ __launch_bounds__(1024) void scan_sums_kernel(const int* __restrict__ bsum,
                                                         int* __restrict__ bpre,
                                                         int* __restrict__ offs_n, int nb) {
    __shared__ int sm[1024];
    int t = threadIdx.x;
    sm[t] = (t < nb) ? bsum[t] : 0;
    __syncthreads();
    for (int off = 1; off < 1024; off <<= 1) {
        int v = (t >= off) ? sm[t - off] : 0;
        __syncthreads();
        sm[t] += v;
        __syncthreads();
    }
    if (t < nb) bpre[t] = (t == 0) ? 0 : sm[t - 1];
    if (t == 1023) offs_n[0] = sm[1023];
}

__global__ __launch_bounds__(256) void block_scan_kernel(const unsigned int* __restrict__ deg,
                                                         const int* __restrict__ bpre,
                                                         int* __restrict__ offs,
                                                         int* __restrict__ cursor, int n) {
    __shared__ int sm[256];
    int t = threadIdx.x;
    int i = blockIdx.x * 256 + t;
    int v = (i < n) ? (int)deg[i] : 0;
    sm[t] = v;
    __syncthreads();
    for (int off = 1; off < 256; off <<= 1) {
        int u = (t >= off) ? sm[t - off] : 0;
        __syncthreads();
        sm[t] += u;
        __syncthreads();
    }
    if (i < n) {
        int ex = bpre[blockIdx.x] + sm[t] - v;  // exclusive prefix
        offs[i] = ex;
        cursor[i] = ex;
    }
}

__global__ __launch_bounds__(256) void fill_csr_kernel(const int* __restrict__ row,
                                                       const int* __restrict__ col,
                                                       const float* __restrict__ dinv,
                                                       int* __restrict__ cursor,
                                                       int* __restrict__ crow,
                                                       float* __restrict__ cw,
                                                       int E, int n) {
    int t = blockIdx.x * 256 + threadIdx.x;
    if (t < E) {
        int r = row[t], c = col[t];
        int pos = atomicAdd(&cursor[c], 1);
        crow[pos] = r;
        cw[pos] = dinv[r] * dinv[c];
    } else if (t < E + n) {
        int i = t - E;
        int pos = atomicAdd(&cursor[i], 1);
        crow[pos] = i;
        float d = dinv[i];
        cw[pos] = d * d;
    }
}

// ---------------- propagation: one wave per node ----------------

__global__ __launch_bounds__(256) void hop_kernel(const int* __restrict__ offs,
                                                  const int* __restrict__ rows,
                                                  const float* __restrict__ wts,
                                                  const float* __restrict__ xin,
                                                  float* __restrict__ xout, int n) {
    int wave = (blockIdx.x * 256 + threadIdx.x) >> 6;
    wave = __builtin_amdgcn_readfirstlane(wave);  // wave-uniform node id -> scalar loads
    if (wave >= n) return;
    const int lane = threadIdx.x & 63;
    const int beg = offs[wave];
    const int end = offs[wave + 1];
    const float2* __restrict__ x2 = (const float2*)xin;
    float ax = 0.f, ay = 0.f;
    int e = beg;
    for (; e + 4 <= end; e += 4) {
        int r0 = rows[e], r1 = rows[e + 1], r2 = rows[e + 2], r3 = rows[e + 3];
        float w0 = wts[e], w1 = wts[e + 1], w2 = wts[e + 2], w3 = wts[e + 3];
        float2 v0 = x2[(size_t)r0 * 64 + lane];
        float2 v1 = x2[(size_t)r1 * 64 + lane];
        float2 v2 = x2[(size_t)r2 * 64 + lane];
        float2 v3 = x2[(size_t)r3 * 64 + lane];
        ax = fmaf(w0, v0.x, ax); ay = fmaf(w0, v0.y, ay);
        ax = fmaf(w1, v1.x, ax); ay = fmaf(w1, v1.y, ay);
        ax = fmaf(w2, v2.x, ax); ay = fmaf(w2, v2.y, ay);
        ax = fmaf(w3, v3.x, ax); ay = fmaf(w3, v3.y, ay);
    }
    for (; e < end; ++e) {
        int r = rows[e];
        float w = wts[e];
        float2 v = x2[(size_t)r * 64 + lane];
        ax = fmaf(w, v.x, ax); ay = fmaf(w, v.y, ay);
    }
    float2 o; o.x = ax; o.y = ay;
    ((float2*)xout)[(size_t)wave * 64 + lane] = o;
}

// ---------------- output ----------------

// out[n,128] = [feature | xs(hops 1..K)] @ W + b, single pass over K-dim = 128*(K+1).
// 64-row tile per block, 256 threads, each thread 8 rows x 4 cols.
__global__ __launch_bounds__(256) void gemm_big_kernel(const float* __restrict__ feature,
                                                       const float* __restrict__ xs,
                                                       const float* __restrict__ W,
                                                       const float* __restrict__ bvec,
                                                       float* __restrict__ out,
                                                       int n, int kk /* = K+1 */) {
    __shared__ float As[64][32];
    __shared__ float Bs[32][128];
    const int tid = threadIdx.x;
    const int bm = blockIdx.x * 64;
    const int tc = tid & 31;   // col group: cols 4*tc .. 4*tc+3
    const int tr = tid >> 5;   // row group: rows tr*8 .. tr*8+7

    float acc[8][4];
    float4 bv = *(const float4*)(bvec + tc * 4);
#pragma unroll
    for (int i = 0; i < 8; ++i) {
        acc[i][0] = bv.x; acc[i][1] = bv.y; acc[i][2] = bv.z; acc[i][3] = bv.w;
    }

    const int r0 = tid >> 2;          // 0..63
    const int c0 = (tid & 3) * 8;     // 0,8,16,24
    int arow = bm + r0;
    if (arow > n - 1) arow = n - 1;   // clamp: safe read, result discarded

    const int KTOT = kk * 128;
    for (int kt = 0; kt < KTOT; kt += 32) {
        const int hop = kt >> 7;
        const int koff = kt & 127;
        const float* Aptr = (hop == 0) ? feature : (xs + (size_t)(hop - 1) * n * 128);
        const float* src = Aptr + (size_t)arow * 128 + koff + c0;
        float4 a0 = *(const float4*)(src);
        float4 a1 = *(const float4*)(src + 4);
        *(float4*)&As[r0][c0]     = a0;
        *(float4*)&As[r0][c0 + 4] = a1;
        const float4* bsrc = (const float4*)(W + (size_t)kt * 128);
        float4* bdst = (float4*)Bs;
#pragma unroll
        for (int q = 0; q < 4; ++q) bdst[tid + q * 256] = bsrc[tid + q * 256];
        __syncthreads();
#pragma unroll
        for (int j4 = 0; j4 < 32; j4 += 4) {
            float4 w0 = *(const float4*)&Bs[j4 + 0][tc * 4];
            float4 w1 = *(const float4*)&Bs[j4 + 1][tc * 4];
            float4 w2 = *(const float4*)&Bs[j4 + 2][tc * 4];
            float4 w3 = *(const float4*)&Bs[j4 + 3][tc * 4];
#pragma unroll
            for (int i = 0; i < 8; ++i) {
                float4 av = *(const float4*)&As[tr * 8 + i][j4];
                acc[i][0] += av.x * w0.x + av.y * w1.x + av.z * w2.x + av.w * w3.x;
                acc[i][1] += av.x * w0.y + av.y * w1.y + av.z * w2.y + av.w * w3.y;
                acc[i][2] += av.x * w0.z + av.y * w1.z + av.z * w2.z + av.w * w3.z;
                acc[i][3] += av.x * w0.w + av.y * w1.w + av.z * w2.w + av.w * w3.w;
            }
        }
        __syncthreads();
    }
#pragma unroll
    for (int i = 0; i < 8; ++i) {
        int row = bm + tr * 8 + i;
        if (row < n) {
            *(float4*)(out + (size_t)row * 128 + tc * 4) =
                make_float4(acc[i][0], acc[i][1], acc[i][2], acc[i][3]);
        }
    }
}

// ---- fallback path (small ws): per-hop accumulating GEMM ----

__global__ __launch_bounds__(256) void init_out_kernel(float* __restrict__ out,
                                                       const float* __restrict__ b, int total) {
    int t = blockIdx.x * 256 + threadIdx.x;
    if (t < total) out[t] = b[t & 127];
}

__global__ __launch_bounds__(256) void gemm_acc_kernel(const float* __restrict__ A,
                                                       const float* __restrict__ B,
                                                       float* __restrict__ C, int n) {
    __shared__ float As[64][32];
    __shared__ float Bs[32][128];
    const int tid = threadIdx.x;
    const int bm = blockIdx.x * 64;
    const int tc = tid & 31;
    const int tr = tid >> 5;

    float acc[8][4];
#pragma unroll
    for (int i = 0; i < 8; ++i)
#pragma unroll
        for (int c = 0; c < 4; ++c) acc[i][c] = 0.f;

    const int r0 = tid >> 2;
    const int c0 = (tid & 3) * 8;
    int arow = bm + r0;
    if (arow > n - 1) arow = n - 1;

    for (int jt = 0; jt < 128; jt += 32) {
        const float* src = A + (size_t)arow * 128 + jt + c0;
        float4 a0 = *(const float4*)(src);
        float4 a1 = *(const float4*)(src + 4);
        *(float4*)&As[r0][c0]     = a0;
        *(float4*)&As[r0][c0 + 4] = a1;
        const float4* bsrc = (const float4*)(B + jt * 128);
        float4* bdst = (float4*)Bs;
#pragma unroll
        for (int q = 0; q < 4; ++q) bdst[tid + q * 256] = bsrc[tid + q * 256];
        __syncthreads();
#pragma unroll
        for (int j4 = 0; j4 < 32; j4 += 4) {
            float4 w0 = *(const float4*)&Bs[j4 + 0][tc * 4];
            float4 w1 = *(const float4*)&Bs[j4 + 1][tc * 4];
            float4 w2 = *(const float4*)&Bs[j4 + 2][tc * 4];
            float4 w3 = *(const float4*)&Bs[j4 + 3][tc * 4];
#pragma unroll
            for (int i = 0; i < 8; ++i) {
                float4 av = *(const float4*)&As[tr * 8 + i][j4];
                acc[i][0] += av.x * w0.x + av.y * w1.x + av.z * w2.x + av.w * w3.x;
                acc[i][1] += av.x * w0.y + av.y * w1.y + av.z * w2.y + av.w * w3.y;
                acc[i][2] += av.x * w0.z + av.y * w1.z + av.z * w2.z + av.w * w3.z;
                acc[i][3] += av.x * w0.w + av.y * w1.w + av.z * w2.w + av.w * w3.w;
            }
        }
        __syncthreads();
    }
#pragma unroll
    for (int i = 0; i < 8; ++i) {
        int row = bm + tr * 8 + i;
        if (row < n) {
            float4* cp = (float4*)(C + (size_t)row * 128 + tc * 4);
            float4 cv = *cp;
            cv.x += acc[i][0]; cv.y += acc[i][1]; cv.z += acc[i][2]; cv.w += acc[i][3];
            *cp = cv;
        }
    }
}

// ---------------- launch ----------------

extern "C" void kernel_launch(void* const* d_in, const int* in_sizes, int n_in,
                              void* d_out, int out_size, void* d_ws, size_t ws_size,
                              hipStream_t stream) {
    const int D = 128;
    const int N = in_sizes[0] / D;
    const int E = in_sizes[1] / 2;
    const int K = in_sizes[2] / (D * D) - 1;  // 8

    const float* feature = (const float*)d_in[0];
    const int*   ei      = (const int*)d_in[1];
    const float* W       = (const float*)d_in[2];
    const float* bvec    = (const float*)d_in[3];
    float* out = (float*)d_out;

    const int* row = ei;
    const int* col = ei + E;

    char* p = (char*)d_ws;
    auto alloc = [&](size_t bytes) {
        char* r = p;
        p += (bytes + 255) & ~(size_t)255;
        return r;
    };
    const int NB = (N + 255) / 256;  // scan blocks (<=1024 supported)
    unsigned int* deg = (unsigned int*)alloc((size_t)N * 4);
    float* dinv       = (float*)alloc((size_t)N * 4);
    int* offs         = (int*)alloc((size_t)(N + 1) * 4);
    int* cursor       = (int*)alloc((size_t)N * 4);
    int* bsum         = (int*)alloc((size_t)NB * 4);
    int* bpre         = (int*)alloc((size_t)NB * 4);
    int* crow         = (int*)alloc((size_t)(E + N) * 4);
    float* cw         = (float*)alloc((size_t)(E + N) * 4);

    size_t used = (size_t)(p - (char*)d_ws);
    size_t need_big = (size_t)K * N * D * 4 + 4096;
    bool big_path = (ws_size - used) >= need_big;

    // graph build
    init_deg_kernel<<<(N + 255) / 256, 256, 0, stream>>>(deg, N);
    count_edges_kernel<<<(E + 255) / 256, 256, 0, stream>>>(col, deg, E);
    dinv_kernel<<<(N + 255) / 256, 256, 0, stream>>>(deg, dinv, N);
    block_sum_kernel<<<NB, 256, 0, stream>>>(deg, bsum, N);
    scan_sums_kernel<<<1, 1024, 0, stream>>>(bsum, bpre, offs + N, NB);
    block_scan_kernel<<<NB, 256, 0, stream>>>(deg, bpre, offs, cursor, N);
    fill_csr_kernel<<<(E + N + 255) / 256, 256, 0, stream>>>(row, col, dinv, cursor, crow, cw, E, N);

    if (big_path) {
        float* xs = (float*)alloc((size_t)K * N * D * 4);  // hop outputs 1..K, contiguous
        const float* xin = feature;
        for (int k = 1; k <= K; ++k) {
            float* xout = xs + (size_t)(k - 1) * N * D;
            hop_kernel<<<(N * 64 + 255) / 256, 256, 0, stream>>>(offs, crow, cw, xin, xout, N);
            xin = xout;
        }
        gemm_big_kernel<<<(N + 63) / 64, 256, 0, stream>>>(feature, xs, W, bvec, out, N, K + 1);
    } else {
        float* xA = (float*)alloc((size_t)N * D * 4);
        float* xB = (float*)alloc((size_t)N * D * 4);
        init_out_kernel<<<(N * D + 255) / 256, 256, 0, stream>>>(out, bvec, N * D);
        gemm_acc_kernel<<<(N + 63) / 64, 256, 0, stream>>>(feature, W, out, N);
        const float* xin = feature;
        float* xout = xA;
        for (int k = 1; k <= K; ++k) {
            hop_kernel<<<(N * 64 + 255) / 256, 256, 0, stream>>>(offs, crow, cw, xin, xout, N);
            gemm_acc_kernel<<<(N + 63) / 64, 256, 0, stream>>>(xout, W + (size_t)k * D * D, out, N);
            xin = xout;
            xout = (xout == xA) ? xB : xA;
        }
    }
}

// Round 8
// 1552.429 us; speedup vs baseline: 1.1400x; 1.0368x over previous
//
#include <hip/hip_runtime.h>
#include <hip/hip_bf16.h>

typedef short short8 __attribute__((ext_vector_type(8)));
typedef float floatx4 __attribute__((ext_vector_type(4)));

__device__ inline unsigned int f2bf(float f) {
    unsigned int u = __float_as_uint(f);
    return (u + 0x7FFFu + ((u >> 16) & 1u)) >> 16;  // round-to-nearest-even bf16
}

// ---------------- graph build ----------------

__global__ __launch_bounds__(256) void init_deg_kernel(unsigned int* __restrict__ deg, int n) {
    int i = blockIdx.x * 256 + threadIdx.x;
    if (i < n) deg[i] = 1u;  // self-loop
}

__global__ __launch_bounds__(256) void count_edges_kernel(const int* __restrict__ col,
                                                          unsigned int* __restrict__ deg, int E) {
    int e = blockIdx.x * 256 + threadIdx.x;
    if (e < E) atomicAdd(&deg[col[e]], 1u);
}

__global__ __launch_bounds__(256) void dinv_kernel(const unsigned int* __restrict__ deg,
                                                   float* __restrict__ dinv, int n) {
    int i = blockIdx.x * 256 + threadIdx.x;
    if (i < n) dinv[i] = 1.0f / sqrtf((float)deg[i]);
}

__global__ __launch_bounds__(256) void block_sum_kernel(const unsigned int* __restrict__ deg,
                                                        int* __restrict__ bsum, int n) {
    __shared__ int sm[256];
    int i = blockIdx.x * 256 + threadIdx.x;
    sm[threadIdx.x] = (i < n) ? (int)deg[i] : 0;
    __syncthreads();
    for (int off = 128; off > 0; off >>= 1) {
        if (threadIdx.x < off) sm[threadIdx.x] += sm[threadIdx.x + off];
        __syncthreads();
    }
    if (threadIdx.x == 0) bsum[blockIdx.x] = sm[0];
}

__global__ __launch_bounds__(1024) void scan_sums_kernel(const int* __restrict__ bsum,
                                                         int* __restrict__ bpre,
                                                         int* __restrict__ offs_n, int nb) {
    __shared__ int sm[1024];
    int t = threadIdx.x;
    sm[t] = (t < nb) ? bsum[t] : 0;
    __syncthreads();
    for (int off = 1; off < 1024; off <<= 1) {
        int v = (t >= off) ? sm[t - off] : 0;
        __syncthreads();
        sm[t] += v;
        __syncthreads();
    }
    if (t < nb) bpre[t] = (t == 0) ? 0 : sm[t - 1];
    if (t == 1023) offs_n[0] = sm[1023];
}

__global__ __launch_bounds__(256) void block_scan_kernel(const unsigned int* __restrict__ deg,
                                                         const int* __restrict__ bpre,
                                                         int* __restrict__ offs,
                                                         int* __restrict__ cursor, int n) {
    __shared__ int sm[256];
    int t = threadIdx.x;
    int i = blockIdx.x * 256 + t;
    int v = (i < n) ? (int)deg[i] : 0;
    sm[t] = v;
    __syncthreads();
    for (int off = 1; off < 256; off <<= 1) {
        int u = (t >= off) ? sm[t - off] : 0;
        __syncthreads();
        sm[t] += u;
        __syncthreads();
    }
    if (i < n) {
        int ex = bpre[blockIdx.x] + sm[t] - v;
        offs[i] = ex;
        cursor[i] = ex;
    }
}

__global__ __launch_bounds__(256) void fill_csr_kernel(const int* __restrict__ row,
                                                       const int* __restrict__ col,
                                                       const float* __restrict__ dinv,
                                                       int* __restrict__ cursor,
                                                       int* __restrict__ crow,
                                                       float* __restrict__ cw,
                                                       int E, int n) {
    int t = blockIdx.x * 256 + threadIdx.x;
    if (t < E) {
        int r = row[t], c = col[t];
        int pos = atomicAdd(&cursor[c], 1);
        crow[pos] = r;
        cw[pos] = dinv[r] * dinv[c];
    } else if (t < E + n) {
        int i = t - E;
        int pos = atomicAdd(&cursor[i], 1);
        crow[pos] = i;
        float d = dinv[i];
        cw[pos] = d * d;
    }
}

// sort each node's CSR segment by source row (ascending) -> L2-coherent sweep in hop_kernel
__global__ __launch_bounds__(256) void sort_csr_kernel(const int* __restrict__ offs,
                                                       int* __restrict__ crow,
                                                       float* __restrict__ cw, int n) {
    int i = blockIdx.x * 256 + threadIdx.x;
    if (i >= n) return;
    int b = offs[i], e = offs[i + 1];
    for (int j = b + 1; j < e; ++j) {
        int r = crow[j];
        float w = cw[j];
        int k = j - 1;
        while (k >= b && crow[k] > r) {
            crow[k + 1] = crow[k];
            cw[k + 1] = cw[k];
            --k;
        }
        crow[k + 1] = r;
        cw[k + 1] = w;
    }
}

// ---------------- one-time converts ----------------

__global__ __launch_bounds__(256) void conv_feat_kernel(const float2* __restrict__ src,
                                                        unsigned int* __restrict__ dst, int total) {
    int i = blockIdx.x * 256 + threadIdx.x;
    if (i < total) {
        float2 v = src[i];
        dst[i] = f2bf(v.x) | (f2bf(v.y) << 16);
    }
}

// WT[c][k] = bf16(W[k][c]); WT is [128][KTOT]
__global__ __launch_bounds__(256) void transpose_w_kernel(const float* __restrict__ W,
                                                          unsigned short* __restrict__ WT,
                                                          int ktot) {
    int t = blockIdx.x * 256 + threadIdx.x;
    if (t < ktot * 128) {
        int k = t >> 7, c = t & 127;
        WT[(size_t)c * ktot + k] = (unsigned short)f2bf(W[t]);
    }
}

// ---------------- propagation: one wave per node ----------------

__global__ __launch_bounds__(256) void hop_kernel(const int* __restrict__ offs,
                                                  const int* __restrict__ rows,
                                                  const float* __restrict__ wts,
                                                  const float* __restrict__ xin,
                                                  float* __restrict__ xout,
                                                  unsigned int* __restrict__ xbf, int n) {
    int wave = (blockIdx.x * 256 + threadIdx.x) >> 6;
    wave = __builtin_amdgcn_readfirstlane(wave);
    if (wave >= n) return;
    const int lane = threadIdx.x & 63;
    const int beg = offs[wave];
    const int end = offs[wave + 1];
    const float2* __restrict__ x2 = (const float2*)xin;
    float ax = 0.f, ay = 0.f;
    int e = beg;
    for (; e + 4 <= end; e += 4) {
        int r0 = rows[e], r1 = rows[e + 1], r2 = rows[e + 2], r3 = rows[e + 3];
        float w0 = wts[e], w1 = wts[e + 1], w2 = wts[e + 2], w3 = wts[e + 3];
        float2 v0 = x2[(size_t)r0 * 64 + lane];
        float2 v1 = x2[(size_t)r1 * 64 + lane];
        float2 v2 = x2[(size_t)r2 * 64 + lane];
        float2 v3 = x2[(size_t)r3 * 64 + lane];
        ax = fmaf(w0, v0.x, ax); ay = fmaf(w0, v0.y, ay);
        ax = fmaf(w1, v1.x, ax); ay = fmaf(w1, v1.y, ay);
        ax = fmaf(w2, v2.x, ax); ay = fmaf(w2, v2.y, ay);
        ax = fmaf(w3, v3.x, ax); ay = fmaf(w3, v3.y, ay);
    }
    for (; e < end; ++e) {
        int r = rows[e];
        float w = wts[e];
        float2 v = x2[(size_t)r * 64 + lane];
        ax = fmaf(w, v.x, ax); ay = fmaf(w, v.y, ay);
    }
    float2 o; o.x = ax; o.y = ay;
    ((float2*)xout)[(size_t)wave * 64 + lane] = o;
    xbf[(size_t)wave * 64 + lane] = f2bf(ax) | (f2bf(ay) << 16);
}

// ---------------- MFMA output GEMM ----------------
// out[n,128] = bf16([feature|xs]) @ bf16(W) + b.  Block: 64 rows x 128 cols, 4 waves.
// Wave w owns rows w*16..w*16+15 as 8 col-fragments of 16x16x32 MFMAs.
// LDS tiles use 8-elem-block XOR swizzle (blk ^= row&7) to kill b128 bank conflicts.
__global__ __launch_bounds__(256) void gemm_mfma_kernel(const unsigned short* __restrict__ featbf,
                                                        const unsigned short* __restrict__ xsbf,
                                                        const unsigned short* __restrict__ WT,
                                                        const float* __restrict__ bvec,
                                                        float* __restrict__ out,
                                                        int n, int kk /* = K+1 */) {
    __shared__ unsigned short Abuf[64 * 64];
    __shared__ unsigned short Bbuf[128 * 64];
    const int tid = threadIdx.x;
    const int bm = blockIdx.x * 64;
    const int w = tid >> 6;
    const int lane = tid & 63;
    const int l15 = lane & 15;
    const int kgrp = lane >> 4;

    floatx4 acc[8];
#pragma unroll
    for (int f = 0; f < 8; ++f) {
        float bv = bvec[f * 16 + l15];
        acc[f] = (floatx4){bv, bv, bv, bv};
    }

    const int sa_row = tid >> 2;   // 0..63
    const int sa_b0 = tid & 3;     // A blocks sa_b0, sa_b0+4
    int ga_row = bm + sa_row;
    if (ga_row > n - 1) ga_row = n - 1;
    const int sb_row = tid >> 1;   // 0..127
    const int sb_b0 = tid & 1;     // B blocks +0,2,4,6

    const int KTOT = kk * 128;
    const int arow16 = w * 16 + l15;
    for (int kt = 0; kt < KTOT; kt += 64) {
        const int hop = kt >> 7;
        const int koff = kt & 127;
        const unsigned short* Abase = (hop == 0) ? featbf : (xsbf + (size_t)(hop - 1) * n * 128);
        const unsigned short* asrc = Abase + (size_t)ga_row * 128 + koff;
#pragma unroll
        for (int q = 0; q < 2; ++q) {
            int blk = sa_b0 + q * 4;
            short8 v = *(const short8*)(asrc + blk * 8);
            *(short8*)&Abuf[sa_row * 64 + ((blk ^ (sa_row & 7)) * 8)] = v;
        }
        const unsigned short* bsrc = WT + (size_t)sb_row * KTOT + kt;
#pragma unroll
        for (int q = 0; q < 4; ++q) {
            int blk = sb_b0 + q * 2;
            short8 v = *(const short8*)(bsrc + blk * 8);
            *(short8*)&Bbuf[sb_row * 64 + ((blk ^ (sb_row & 7)) * 8)] = v;
        }
        __syncthreads();
#pragma unroll
        for (int s = 0; s < 2; ++s) {
            int ablk = (s * 4 + kgrp) ^ (arow16 & 7);
            short8 a = *(const short8*)&Abuf[arow16 * 64 + ablk * 8];
#pragma unroll
            for (int f = 0; f < 8; ++f) {
                int c = f * 16 + l15;
                int bblk = (s * 4 + kgrp) ^ (c & 7);
                short8 b = *(const short8*)&Bbuf[c * 64 + bblk * 8];
                acc[f] = __builtin_amdgcn_mfma_f32_16x16x32_bf16(a, b, acc[f], 0, 0, 0);
            }
        }
        __syncthreads();
    }
    // C/D layout (HW-verified): row=(lane>>4)*4+reg, col=lane&15
#pragma unroll
    for (int f = 0; f < 8; ++f) {
        int ocol = f * 16 + l15;
#pragma unroll
        for (int r = 0; r < 4; ++r) {
            int orow = bm + w * 16 + kgrp * 4 + r;
            if (orow < n) out[(size_t)orow * 128 + ocol] = acc[f][r];
        }
    }
}

// ---- fallback (small ws): old fp32 accumulating GEMM path ----

__global__ __launch_bounds__(256) void init_out_kernel(float* __restrict__ out,
                                                       const float* __restrict__ b, int total) {
    int t = blockIdx.x * 256 + threadIdx.x;
    if (t < total) out[t] = b[t & 127];
}

__global__ __launch_bounds__(256) void gemm_acc_kernel(const float* __restrict__ A,
                                                       const float* __restrict__ B,
                                                       float* __restrict__ C, int n) {
    __shared__ float As[64][32];
    __shared__ float Bs[32][128];
    const int tid = threadIdx.x;
    const int bm = blockIdx.x * 64;
    const int tc = tid & 31;
    const int tr = tid >> 5;

    float acc[8][4];
#pragma unroll
    for (int i = 0; i < 8; ++i)
#pragma unroll
        for (int c = 0; c < 4; ++c) acc[i][c] = 0.f;

    const int r0 = tid >> 2;
    const int c0 = (tid & 3) * 8;
    int arow = bm + r0;
    if (arow > n - 1) arow = n - 1;

    for (int jt = 0; jt < 128; jt += 32) {
        const float* src = A + (size_t)arow * 128 + jt + c0;
        float4 a0 = *(const float4*)(src);
        float4 a1 = *(const float4*)(src + 4);
        *(float4*)&As[r0][c0]     = a0;
        *(float4*)&As[r0][c0 + 4] = a1;
        const float4* bsrc = (const float4*)(B + jt * 128);
        float4* bdst = (float4*)Bs;
#pragma unroll
        for (int q = 0; q < 4; ++q) bdst[tid + q * 256] = bsrc[tid + q * 256];
        __syncthreads();
#pragma unroll
        for (int j4 = 0; j4 < 32; j4 += 4) {
            float4 w0 = *(const float4*)&Bs[j4 + 0][tc * 4];
            float4 w1 = *(const float4*)&Bs[j4 + 1][tc * 4];
            float4 w2 = *(const float4*)&Bs[j4 + 2][tc * 4];
            float4 w3 = *(const float4*)&Bs[j4 + 3][tc * 4];
#pragma unroll
            for (int i = 0; i < 8; ++i) {
                float4 av = *(const float4*)&As[tr * 8 + i][j4];
                acc[i][0] += av.x * w0.x + av.y * w1.x + av.z * w2.x + av.w * w3.x;
                acc[i][1] += av.x * w0.y + av.y * w1.y + av.z * w2.y + av.w * w3.y;
                acc[i][2] += av.x * w0.z + av.y * w1.z + av.z * w2.z + av.w * w3.z;
                acc[i][3] += av.x * w0.w + av.y * w1.w + av.z * w2.w + av.w * w3.w;
            }
        }
        __syncthreads();
    }
#pragma unroll
    for (int i = 0; i < 8; ++i) {
        int row = bm + tr * 8 + i;
        if (row < n) {
            float4* cp = (float4*)(C + (size_t)row * 128 + tc * 4);
            float4 cv = *cp;
            cv.x += acc[i][0]; cv.y += acc[i][1]; cv.z += acc[i][2]; cv.w += acc[i][3];
            *cp = cv;
        }
    }
}

__global__ __launch_bounds__(256) void hop_plain_kernel(const int* __restrict__ offs,
                                                        const int* __restrict__ rows,
                                                        const float* __restrict__ wts,
                                                        const float* __restrict__ xin,
                                                        float* __restrict__ xout, int n) {
    int wave = (blockIdx.x * 256 + threadIdx.x) >> 6;
    wave = __builtin_amdgcn_readfirstlane(wave);
    if (wave >= n) return;
    const int lane = threadIdx.x & 63;
    const int beg = offs[wave];
    const int end = offs[wave + 1];
    const float2* __restrict__ x2 = (const float2*)xin;
    float ax = 0.f, ay = 0.f;
    for (int e = beg; e < end; ++e) {
        int r = rows[e];
        float w = wts[e];
        float2 v = x2[(size_t)r * 64 + lane];
        ax = fmaf(w, v.x, ax); ay = fmaf(w, v.y, ay);
    }
    float2 o; o.x = ax; o.y = ay;
    ((float2*)xout)[(size_t)wave * 64 + lane] = o;
}

// ---------------- launch ----------------

extern "C" void kernel_launch(void* const* d_in, const int* in_sizes, int n_in,
                              void* d_out, int out_size, void* d_ws, size_t ws_size,
                              hipStream_t stream) {
    const int D = 128;
    const int N = in_sizes[0] / D;
    const int E = in_sizes[1] / 2;
    const int K = in_sizes[2] / (D * D) - 1;  // 8
    const int KTOT = (K + 1) * D;             // 1152

    const float* feature = (const float*)d_in[0];
    const int*   ei      = (const int*)d_in[1];
    const float* W       = (const float*)d_in[2];
    const float* bvec    = (const float*)d_in[3];
    float* out = (float*)d_out;

    const int* row = ei;
    const int* col = ei + E;

    char* p = (char*)d_ws;
    auto alloc = [&](size_t bytes) {
        char* r = p;
        p += (bytes + 255) & ~(size_t)255;
        return r;
    };
    const int NB = (N + 255) / 256;
    unsigned int* deg = (unsigned int*)alloc((size_t)N * 4);
    float* dinv       = (float*)alloc((size_t)N * 4);
    int* offs         = (int*)alloc((size_t)(N + 1) * 4);
    int* cursor       = (int*)alloc((size_t)N * 4);
    int* bsum         = (int*)alloc((size_t)NB * 4);
    int* bpre         = (int*)alloc((size_t)NB * 4);
    int* crow         = (int*)alloc((size_t)(E + N) * 4);
    float* cw         = (float*)alloc((size_t)(E + N) * 4);

    size_t used = (size_t)(p - (char*)d_ws);
    // new path: xA,xB fp32 ping-pong + featbf + xsbf + WT
    size_t need_new = 2 * (size_t)N * D * 4 + (size_t)N * D * 2 + (size_t)K * N * D * 2 +
                      (size_t)KTOT * D * 2 + 8 * 4096;
    bool mfma_path = (ws_size - used) >= need_new;

    // graph build
    init_deg_kernel<<<(N + 255) / 256, 256, 0, stream>>>(deg, N);
    count_edges_kernel<<<(E + 255) / 256, 256, 0, stream>>>(col, deg, E);
    dinv_kernel<<<(N + 255) / 256, 256, 0, stream>>>(deg, dinv, N);
    block_sum_kernel<<<NB, 256, 0, stream>>>(deg, bsum, N);
    scan_sums_kernel<<<1, 1024, 0, stream>>>(bsum, bpre, offs + N, NB);
    block_scan_kernel<<<NB, 256, 0, stream>>>(deg, bpre, offs, cursor, N);
    fill_csr_kernel<<<(E + N + 255) / 256, 256, 0, stream>>>(row, col, dinv, cursor, crow, cw, E, N);
    sort_csr_kernel<<<(N + 255) / 256, 256, 0, stream>>>(offs, crow, cw, N);

    if (mfma_path) {
        float* xA               = (float*)alloc((size_t)N * D * 4);
        float* xB               = (float*)alloc((size_t)N * D * 4);
        unsigned int* featbf    = (unsigned int*)alloc((size_t)N * D * 2);   // N*64 uints
        unsigned short* xsbf    = (unsigned short*)alloc((size_t)K * N * D * 2);
        unsigned short* WT      = (unsigned short*)alloc((size_t)KTOT * D * 2);

        conv_feat_kernel<<<(N * 64 + 255) / 256, 256, 0, stream>>>((const float2*)feature, featbf, N * 64);
        transpose_w_kernel<<<(KTOT * D + 255) / 256, 256, 0, stream>>>(W, WT, KTOT);

        const float* xin = feature;
        float* xout = xA;
        for (int k = 1; k <= K; ++k) {
            unsigned int* xbf = (unsigned int*)(xsbf + (size_t)(k - 1) * N * D);
            hop_kernel<<<(N * 64 + 255) / 256, 256, 0, stream>>>(offs, crow, cw, xin, xout, xbf, N);
            xin = xout;
            xout = (xout == xA) ? xB : xA;
        }
        gemm_mfma_kernel<<<(N + 63) / 64, 256, 0, stream>>>(
            (const unsigned short*)featbf, xsbf, WT, bvec, out, N, K + 1);
    } else {
        float* xA = (float*)alloc((size_t)N * D * 4);
        float* xB = (float*)alloc((size_t)N * D * 4);
        init_out_kernel<<<(N * D + 255) / 256, 256, 0, stream>>>(out, bvec, N * D);
        gemm_acc_kernel<<<(N + 63) / 64, 256, 0, stream>>>(feature, W, out, N);
        const float* xin = feature;
        float* xout = xA;
        for (int k = 1; k <= K; ++k) {
            hop_plain_kernel<<<(N * 64 + 255) / 256, 256, 0, stream>>>(offs, crow, cw, xin, xout, N);
            gemm_acc_kernel<<<(N + 63) / 64, 256, 0, stream>>>(xout, W + (size_t)k * D * D, out, N);
            xin = xout;
            xout = (xout == xA) ? xB : xA;
        }
    }
}

// Round 12
// 734.264 us; speedup vs baseline: 2.4102x; 2.1143x over previous
//
#include <hip/hip_runtime.h>
#include <hip/hip_bf16.h>

typedef short short8 __attribute__((ext_vector_type(8)));
typedef float floatx4 __attribute__((ext_vector_type(4)));

__device__ inline unsigned int f2bf(float f) {
    unsigned int u = __float_as_uint(f);
    return (u + 0x7FFFu + ((u >> 16) & 1u)) >> 16;  // round-to-nearest-even bf16
}

// ---------------- graph build ----------------

__global__ __launch_bounds__(256) void init_deg_kernel(unsigned int* __restrict__ deg, int n) {
    int i = blockIdx.x * 256 + threadIdx.x;
    if (i < n) deg[i] = 1u;  // self-loop
}

__global__ __launch_bounds__(256) void count_edges_kernel(const int* __restrict__ col,
                                                          unsigned int* __restrict__ deg, int E) {
    int e = blockIdx.x * 256 + threadIdx.x;
    if (e < E) atomicAdd(&deg[col[e]], 1u);
}

__global__ __launch_bounds__(256) void dinv_kernel(const unsigned int* __restrict__ deg,
                                                   float* __restrict__ dinv, int n) {
    int i = blockIdx.x * 256 + threadIdx.x;
    if (i < n) dinv[i] = 1.0f / sqrtf((float)deg[i]);
}

__global__ __launch_bounds__(256) void block_sum_kernel(const unsigned int* __restrict__ deg,
                                                        int* __restrict__ bsum, int n) {
    __shared__ int sm[256];
    int i = blockIdx.x * 256 + threadIdx.x;
    sm[threadIdx.x] = (i < n) ? (int)deg[i] : 0;
    __syncthreads();
    for (int off = 128; off > 0; off >>= 1) {
        if (threadIdx.x < off) sm[threadIdx.x] += sm[threadIdx.x + off];
        __syncthreads();
    }
    if (threadIdx.x == 0) bsum[blockIdx.x] = sm[0];
}

__global__ __launch_bounds__(1024) void scan_sums_kernel(const int* __restrict__ bsum,
                                                         int* __restrict__ bpre,
                                                         int* __restrict__ offs_n, int nb) {
    __shared__ int sm[1024];
    int t = threadIdx.x;
    sm[t] = (t < nb) ? bsum[t] : 0;
    __syncthreads();
    for (int off = 1; off < 1024; off <<= 1) {
        int v = (t >= off) ? sm[t - off] : 0;
        __syncthreads();
        sm[t] += v;
        __syncthreads();
    }
    if (t < nb) bpre[t] = (t == 0) ? 0 : sm[t - 1];
    if (t == 1023) offs_n[0] = sm[1023];
}

__global__ __launch_bounds__(256) void block_scan_kernel(const unsigned int* __restrict__ deg,
                                                         const int* __restrict__ bpre,
                                                         int* __restrict__ offs,
                                                         int* __restrict__ cursor, int n) {
    __shared__ int sm[256];
    int t = threadIdx.x;
    int i = blockIdx.x * 256 + t;
    int v = (i < n) ? (int)deg[i] : 0;
    sm[t] = v;
    __syncthreads();
    for (int off = 1; off < 256; off <<= 1) {
        int u = (t >= off) ? sm[t - off] : 0;
        __syncthreads();
        sm[t] += u;
        __syncthreads();
    }
    if (i < n) {
        int ex = bpre[blockIdx.x] + sm[t] - v;
        offs[i] = ex;
        cursor[i] = ex;
    }
}

__global__ __launch_bounds__(256) void fill_csr_kernel(const int* __restrict__ row,
                                                       const int* __restrict__ col,
                                                       const float* __restrict__ dinv,
                                                       int* __restrict__ cursor,
                                                       int* __restrict__ crow,
                                                       float* __restrict__ cw,
                                                       int E, int n) {
    int t = blockIdx.x * 256 + threadIdx.x;
    if (t < E) {
        int r = row[t], c = col[t];
        int pos = atomicAdd(&cursor[c], 1);
        crow[pos] = r;
        cw[pos] = dinv[r] * dinv[c];
    } else if (t < E + n) {
        int i = t - E;
        int pos = atomicAdd(&cursor[i], 1);
        crow[pos] = i;
        float d = dinv[i];
        cw[pos] = d * d;
    }
}

// ---------------- one-time converts ----------------

__global__ __launch_bounds__(256) void conv_feat_kernel(const float2* __restrict__ src,
                                                        unsigned int* __restrict__ dst, int total) {
    int i = blockIdx.x * 256 + threadIdx.x;
    if (i < total) {
        float2 v = src[i];
        dst[i] = f2bf(v.x) | (f2bf(v.y) << 16);
    }
}

// WT[c][k] = bf16(W[k][c]); WT is [128][KTOT]
__global__ __launch_bounds__(256) void transpose_w_kernel(const float* __restrict__ W,
                                                          unsigned short* __restrict__ WT,
                                                          int ktot) {
    int t = blockIdx.x * 256 + threadIdx.x;
    if (t < ktot * 128) {
        int k = t >> 7, c = t & 127;
        WT[(size_t)c * ktot + k] = (unsigned short)f2bf(W[t]);
    }
}

// ---------------- propagation: one wave per node, bf16 gathers ----------------
// xin/xout: packed 2xbf16 per uint, row = 64 uints (128 features). fp32 accumulate.

__global__ __launch_bounds__(256) void hop_bf_kernel(const int* __restrict__ offs,
                                                     const int* __restrict__ rows,
                                                     const float* __restrict__ wts,
                                                     const unsigned int* __restrict__ xin,
                                                     unsigned int* __restrict__ xout, int n) {
    int wave = (blockIdx.x * 256 + threadIdx.x) >> 6;
    wave = __builtin_amdgcn_readfirstlane(wave);  // wave-uniform -> scalar CSR loads
    if (wave >= n) return;
    const int lane = threadIdx.x & 63;
    const int beg = offs[wave];
    const int end = offs[wave + 1];
    float ax = 0.f, ay = 0.f;
    int e = beg;
    for (; e + 4 <= end; e += 4) {
        int r0 = rows[e], r1 = rows[e + 1], r2 = rows[e + 2], r3 = rows[e + 3];
        float w0 = wts[e], w1 = wts[e + 1], w2 = wts[e + 2], w3 = wts[e + 3];
        unsigned int v0 = xin[(size_t)r0 * 64 + lane];
        unsigned int v1 = xin[(size_t)r1 * 64 + lane];
        unsigned int v2 = xin[(size_t)r2 * 64 + lane];
        unsigned int v3 = xin[(size_t)r3 * 64 + lane];
        ax = fmaf(w0, __uint_as_float(v0 << 16), ax);
        ay = fmaf(w0, __uint_as_float(v0 & 0xFFFF0000u), ay);
        ax = fmaf(w1, __uint_as_float(v1 << 16), ax);
        ay = fmaf(w1, __uint_as_float(v1 & 0xFFFF0000u), ay);
        ax = fmaf(w2, __uint_as_float(v2 << 16), ax);
        ay = fmaf(w2, __uint_as_float(v2 & 0xFFFF0000u), ay);
        ax = fmaf(w3, __uint_as_float(v3 << 16), ax);
        ay = fmaf(w3, __uint_as_float(v3 & 0xFFFF0000u), ay);
    }
    for (; e < end; ++e) {
        int r = rows[e];
        float w = wts[e];
        unsigned int v = xin[(size_t)r * 64 + lane];
        ax = fmaf(w, __uint_as_float(v << 16), ax);
        ay = fmaf(w, __uint_as_float(v & 0xFFFF0000u), ay);
    }
    xout[(size_t)wave * 64 + lane] = f2bf(ax) | (f2bf(ay) << 16);
}

// ---------------- MFMA output GEMM ----------------
// out[n,128] = bf16([feature|xs]) @ bf16(W) + b.  Block: 64 rows x 128 cols, 4 waves.
// LDS tiles use 8-elem-block XOR swizzle (blk ^= row&7) to kill b128 bank conflicts.
__global__ __launch_bounds__(256) void gemm_mfma_kernel(const unsigned short* __restrict__ featbf,
                                                        const unsigned short* __restrict__ xsbf,
                                                        const unsigned short* __restrict__ WT,
                                                        const float* __restrict__ bvec,
                                                        float* __restrict__ out,
                                                        int n, int kk /* = K+1 */) {
    __shared__ unsigned short Abuf[64 * 64];
    __shared__ unsigned short Bbuf[128 * 64];
    const int tid = threadIdx.x;
    const int bm = blockIdx.x * 64;
    const int w = tid >> 6;
    const int lane = tid & 63;
    const int l15 = lane & 15;
    const int kgrp = lane >> 4;

    floatx4 acc[8];
#pragma unroll
    for (int f = 0; f < 8; ++f) {
        float bv = bvec[f * 16 + l15];
        acc[f] = (floatx4){bv, bv, bv, bv};
    }

    const int sa_row = tid >> 2;   // 0..63
    const int sa_b0 = tid & 3;     // A blocks sa_b0, sa_b0+4
    int ga_row = bm + sa_row;
    if (ga_row > n - 1) ga_row = n - 1;
    const int sb_row = tid >> 1;   // 0..127
    const int sb_b0 = tid & 1;     // B blocks +0,2,4,6

    const int KTOT = kk * 128;
    const int arow16 = w * 16 + l15;
    for (int kt = 0; kt < KTOT; kt += 64) {
        const int hop = kt >> 7;
        const int koff = kt & 127;
        const unsigned short* Abase = (hop == 0) ? featbf : (xsbf + (size_t)(hop - 1) * n * 128);
        const unsigned short* asrc = Abase + (size_t)ga_row * 128 + koff;
#pragma unroll
        for (int q = 0; q < 2; ++q) {
            int blk = sa_b0 + q * 4;
            short8 v = *(const short8*)(asrc + blk * 8);
            *(short8*)&Abuf[sa_row * 64 + ((blk ^ (sa_row & 7)) * 8)] = v;
        }
        const unsigned short* bsrc = WT + (size_t)sb_row * KTOT + kt;
#pragma unroll
        for (int q = 0; q < 4; ++q) {
            int blk = sb_b0 + q * 2;
            short8 v = *(const short8*)(bsrc + blk * 8);
            *(short8*)&Bbuf[sb_row * 64 + ((blk ^ (sb_row & 7)) * 8)] = v;
        }
        __syncthreads();
#pragma unroll
        for (int s = 0; s < 2; ++s) {
            int ablk = (s * 4 + kgrp) ^ (arow16 & 7);
            short8 a = *(const short8*)&Abuf[arow16 * 64 + ablk * 8];
#pragma unroll
            for (int f = 0; f < 8; ++f) {
                int c = f * 16 + l15;
                int bblk = (s * 4 + kgrp) ^ (c & 7);
                short8 b = *(const short8*)&Bbuf[c * 64 + bblk * 8];
                acc[f] = __builtin_amdgcn_mfma_f32_16x16x32_bf16(a, b, acc[f], 0, 0, 0);
            }
        }
        __syncthreads();
    }
    // C/D layout (HW-verified): row=(lane>>4)*4+reg, col=lane&15
#pragma unroll
    for (int f = 0; f < 8; ++f) {
        int ocol = f * 16 + l15;
#pragma unroll
        for (int r = 0; r < 4; ++r) {
            int orow = bm + w * 16 + kgrp * 4 + r;
            if (orow < n) out[(size_t)orow * 128 + ocol] = acc[f][r];
        }
    }
}

// ---- fallback (small ws): old fp32 accumulating GEMM path ----

__global__ __launch_bounds__(256) void init_out_kernel(float* __restrict__ out,
                                                       const float* __restrict__ b, int total) {
    int t = blockIdx.x * 256 + threadIdx.x;
    if (t < total) out[t] = b[t & 127];
}

__global__ __launch_bounds__(256) void gemm_acc_kernel(const float* __restrict__ A,
                                                       const float* __restrict__ B,
                                                       float* __restrict__ C, int n) {
    __shared__ float As[64][32];
    __shared__ float Bs[32][128];
    const int tid = threadIdx.x;
    const int bm = blockIdx.x * 64;
    const int tc = tid & 31;
    const int tr = tid >> 5;

    float acc[8][4];
#pragma unroll
    for (int i = 0; i < 8; ++i)
#pragma unroll
        for (int c = 0; c < 4; ++c) acc[i][c] = 0.f;

    const int r0 = tid >> 2;
    const int c0 = (tid & 3) * 8;
    int arow = bm + r0;
    if (arow > n - 1) arow = n - 1;

    for (int jt = 0; jt < 128; jt += 32) {
        const float* src = A + (size_t)arow * 128 + jt + c0;
        float4 a0 = *(const float4*)(src);
        float4 a1 = *(const float4*)(src + 4);
        *(float4*)&As[r0][c0]     = a0;
        *(float4*)&As[r0][c0 + 4] = a1;
        const float4* bsrc = (const float4*)(B + jt * 128);
        float4* bdst = (float4*)Bs;
#pragma unroll
        for (int q = 0; q < 4; ++q) bdst[tid + q * 256] = bsrc[tid + q * 256];
        __syncthreads();
#pragma unroll
        for (int j4 = 0; j4 < 32; j4 += 4) {
            float4 w0 = *(const float4*)&Bs[j4 + 0][tc * 4];
            float4 w1 = *(const float4*)&Bs[j4 + 1][tc * 4];
            float4 w2 = *(const float4*)&Bs[j4 + 2][tc * 4];
            float4 w3 = *(const float4*)&Bs[j4 + 3][tc * 4];
#pragma unroll
            for (int i = 0; i < 8; ++i) {
                float4 av = *(const float4*)&As[tr * 8 + i][j4];
                acc[i][0] += av.x * w0.x + av.y * w1.x + av.z * w2.x + av.w * w3.x;
                acc[i][1] += av.x * w0.y + av.y * w1.y + av.z * w2.y + av.w * w3.y;
                acc[i][2] += av.x * w0.z + av.y * w1.z + av.z * w2.z + av.w * w3.z;
                acc[i][3] += av.x * w0.w + av.y * w1.w + av.z * w2.w + av.w * w3.w;
            }
        }
        __syncthreads();
    }
#pragma unroll
    for (int i = 0; i < 8; ++i) {
        int row = bm + tr * 8 + i;
        if (row < n) {
            float4* cp = (float4*)(C + (size_t)row * 128 + tc * 4);
            float4 cv = *cp;
            cv.x += acc[i][0]; cv.y += acc[i][1]; cv.z += acc[i][2]; cv.w += acc[i][3];
            *cp = cv;
        }
    }
}

__global__ __launch_bounds__(256) void hop_plain_kernel(const int* __restrict__ offs,
                                                        const int* __restrict__ rows,
                                                        const float* __restrict__ wts,
                                                        const float* __restrict__ xin,
                                                        float* __restrict__ xout, int n) {
    int wave = (blockIdx.x * 256 + threadIdx.x) >> 6;
    wave = __builtin_amdgcn_readfirstlane(wave);
    if (wave >= n) return;
    const int lane = threadIdx.x & 63;
    const int beg = offs[wave];
    const int end = offs[wave + 1];
    const float2* __restrict__ x2 = (const float2*)xin;
    float ax = 0.f, ay = 0.f;
    for (int e = beg; e < end; ++e) {
        int r = rows[e];
        float w = wts[e];
        float2 v = x2[(size_t)r * 64 + lane];
        ax = fmaf(w, v.x, ax); ay = fmaf(w, v.y, ay);
    }
    float2 o; o.x = ax; o.y = ay;
    ((float2*)xout)[(size_t)wave * 64 + lane] = o;
}

// ---------------- launch ----------------

extern "C" void kernel_launch(void* const* d_in, const int* in_sizes, int n_in,
                              void* d_out, int out_size, void* d_ws, size_t ws_size,
                              hipStream_t stream) {
    const int D = 128;
    const int N = in_sizes[0] / D;
    const int E = in_sizes[1] / 2;
    const int K = in_sizes[2] / (D * D) - 1;  // 8
    const int KTOT = (K + 1) * D;             // 1152

    const float* feature = (const float*)d_in[0];
    const int*   ei      = (const int*)d_in[1];
    const float* W       = (const float*)d_in[2];
    const float* bvec    = (const float*)d_in[3];
    float* out = (float*)d_out;

    const int* row = ei;
    const int* col = ei + E;

    char* p = (char*)d_ws;
    auto alloc = [&](size_t bytes) {
        char* r = p;
        p += (bytes + 255) & ~(size_t)255;
        return r;
    };
    const int NB = (N + 255) / 256;
    unsigned int* deg = (unsigned int*)alloc((size_t)N * 4);
    float* dinv       = (float*)alloc((size_t)N * 4);
    int* offs         = (int*)alloc((size_t)(N + 1) * 4);
    int* cursor       = (int*)alloc((size_t)N * 4);
    int* bsum         = (int*)alloc((size_t)NB * 4);
    int* bpre         = (int*)alloc((size_t)NB * 4);
    int* crow         = (int*)alloc((size_t)(E + N) * 4);
    float* cw         = (float*)alloc((size_t)(E + N) * 4);

    size_t used = (size_t)(p - (char*)d_ws);
    // mfma path: featbf + xsbf + WT
    size_t need_new = (size_t)N * D * 2 + (size_t)K * N * D * 2 + (size_t)KTOT * D * 2 + 8 * 4096;
    bool mfma_path = (ws_size - used) >= need_new;

    // graph build
    init_deg_kernel<<<(N + 255) / 256, 256, 0, stream>>>(deg, N);
    count_edges_kernel<<<(E + 255) / 256, 256, 0, stream>>>(col, deg, E);
    dinv_kernel<<<(N + 255) / 256, 256, 0, stream>>>(deg, dinv, N);
    block_sum_kernel<<<NB, 256, 0, stream>>>(deg, bsum, N);
    scan_sums_kernel<<<1, 1024, 0, stream>>>(bsum, bpre, offs + N, NB);
    block_scan_kernel<<<NB, 256, 0, stream>>>(deg, bpre, offs, cursor, N);
    fill_csr_kernel<<<(E + N + 255) / 256, 256, 0, stream>>>(row, col, dinv, cursor, crow, cw, E, N);

    if (mfma_path) {
        unsigned int* featbf = (unsigned int*)alloc((size_t)N * D * 2);  // N*64 uints
        unsigned short* xsbf = (unsigned short*)alloc((size_t)K * N * D * 2);
        unsigned short* WT   = (unsigned short*)alloc((size_t)KTOT * D * 2);

        conv_feat_kernel<<<(N * 64 + 255) / 256, 256, 0, stream>>>((const float2*)feature, featbf, N * 64);
        transpose_w_kernel<<<(KTOT * D + 255) / 256, 256, 0, stream>>>(W, WT, KTOT);

        const unsigned int* xin = featbf;
        for (int k = 1; k <= K; ++k) {
            unsigned int* xo = (unsigned int*)(xsbf + (size_t)(k - 1) * N * D);
            hop_bf_kernel<<<(N * 64 + 255) / 256, 256, 0, stream>>>(offs, crow, cw, xin, xo, N);
            xin = xo;
        }
        gemm_mfma_kernel<<<(N + 63) / 64, 256, 0, stream>>>(
            (const unsigned short*)featbf, xsbf, WT, bvec, out, N, K + 1);
    } else {
        float* xA = (float*)alloc((size_t)N * D * 4);
        float* xB = (float*)alloc((size_t)N * D * 4);
        init_out_kernel<<<(N * D + 255) / 256, 256, 0, stream>>>(out, bvec, N * D);
        gemm_acc_kernel<<<(N + 63) / 64, 256, 0, stream>>>(feature, W, out, N);
        const float* xin = feature;
        float* xout = xA;
        for (int k = 1; k <= K; ++k) {
            hop_plain_kernel<<<(N * 64 + 255) / 256, 256, 0, stream>>>(offs, crow, cw, xin, xout, N);
            gemm_acc_kernel<<<(N + 63) / 64, 256, 0, stream>>>(xout, W + (size_t)k * D * D, out, N);
            xin = xout;
            xout = (xout == xA) ? xB : xA;
        }
    }
}

// Round 14
// 686.470 us; speedup vs baseline: 2.5780x; 1.0696x over previous
//
#include <hip/hip_runtime.h>
#include <hip/hip_bf16.h>

typedef short short8 __attribute__((ext_vector_type(8)));
typedef float floatx4 __attribute__((ext_vector_type(4)));

__device__ inline unsigned int f2bf(float f) {
    unsigned int u = __float_as_uint(f);
    return (u + 0x7FFFu + ((u >> 16) & 1u)) >> 16;  // round-to-nearest-even bf16
}

// ---------------- graph build ----------------

__global__ __launch_bounds__(256) void init_deg_kernel(unsigned int* __restrict__ deg, int n) {
    int i = blockIdx.x * 256 + threadIdx.x;
    if (i < n) deg[i] = 1u;  // self-loop
}

__global__ __launch_bounds__(256) void count_edges_kernel(const int* __restrict__ col,
                                                          unsigned int* __restrict__ deg, int E) {
    int e = blockIdx.x * 256 + threadIdx.x;
    if (e < E) atomicAdd(&deg[col[e]], 1u);
}

__global__ __launch_bounds__(256) void dinv_kernel(const unsigned int* __restrict__ deg,
                                                   float* __restrict__ dinv, int n) {
    int i = blockIdx.x * 256 + threadIdx.x;
    if (i < n) dinv[i] = 1.0f / sqrtf((float)deg[i]);
}

__global__ __launch_bounds__(256) void block_sum_kernel(const unsigned int* __restrict__ deg,
                                                        int* __restrict__ bsum, int n) {
    __shared__ int sm[256];
    int i = blockIdx.x * 256 + threadIdx.x;
    sm[threadIdx.x] = (i < n) ? (int)deg[i] : 0;
    __syncthreads();
    for (int off = 128; off > 0; off >>= 1) {
        if (threadIdx.x < off) sm[threadIdx.x] += sm[threadIdx.x + off];
        __syncthreads();
    }
    if (threadIdx.x == 0) bsum[blockIdx.x] = sm[0];
}

__global__ __launch_bounds__(1024) void scan_sums_kernel(const int* __restrict__ bsum,
                                                         int* __restrict__ bpre,
                                                         int* __restrict__ offs_n, int nb) {
    __shared__ int sm[1024];
    int t = threadIdx.x;
    sm[t] = (t < nb) ? bsum[t] : 0;
    __syncthreads();
    for (int off = 1; off < 1024; off <<= 1) {
        int v = (t >= off) ? sm[t - off] : 0;
        __syncthreads();
        sm[t] += v;
        __syncthreads();
    }
    if (t < nb) bpre[t] = (t == 0) ? 0 : sm[t - 1];
    if (t == 1023) offs_n[0] = sm[1023];
}

__global__ __launch_bounds__(256) void block_scan_kernel(const unsigned int* __restrict__ deg,
                                                         const int* __restrict__ bpre,
                                                         int* __restrict__ offs,
                                                         int* __restrict__ cursor, int n) {
    __shared__ int sm[256];
    int t = threadIdx.x;
    int i = blockIdx.x * 256 + t;
    int v = (i < n) ? (int)deg[i] : 0;
    sm[t] = v;
    __syncthreads();
    for (int off = 1; off < 256; off <<= 1) {
        int u = (t >= off) ? sm[t - off] : 0;
        __syncthreads();
        sm[t] += u;
        __syncthreads();
    }
    if (i < n) {
        int ex = bpre[blockIdx.x] + sm[t] - v;
        offs[i] = ex;
        cursor[i] = ex;
    }
}

// packed CSR record: .x = source row, .y = weight bits  (single 8B scatter store)
__global__ __launch_bounds__(256) void fill_csr_kernel(const int* __restrict__ row,
                                                       const int* __restrict__ col,
                                                       const float* __restrict__ dinv,
                                                       int* __restrict__ cursor,
                                                       uint2* __restrict__ crw,
                                                       int E, int n) {
    int t = blockIdx.x * 256 + threadIdx.x;
    if (t < E) {
        int r = row[t], c = col[t];
        int pos = atomicAdd(&cursor[c], 1);
        uint2 rec;
        rec.x = (unsigned int)r;
        rec.y = __float_as_uint(dinv[r] * dinv[c]);
        crw[pos] = rec;
    } else if (t < E + n) {
        int i = t - E;
        int pos = atomicAdd(&cursor[i], 1);
        float d = dinv[i];
        uint2 rec;
        rec.x = (unsigned int)i;
        rec.y = __float_as_uint(d * d);
        crw[pos] = rec;
    }
}

// ---------------- one-time converts ----------------

__global__ __launch_bounds__(256) void conv_feat_kernel(const float2* __restrict__ src,
                                                        unsigned int* __restrict__ dst, int total) {
    int i = blockIdx.x * 256 + threadIdx.x;
    if (i < total) {
        float2 v = src[i];
        dst[i] = f2bf(v.x) | (f2bf(v.y) << 16);
    }
}

// WT[c][k] = bf16(W[k][c]); WT is [128][KTOT]
__global__ __launch_bounds__(256) void transpose_w_kernel(const float* __restrict__ W,
                                                          unsigned short* __restrict__ WT,
                                                          int ktot) {
    int t = blockIdx.x * 256 + threadIdx.x;
    if (t < ktot * 128) {
        int k = t >> 7, c = t & 127;
        WT[(size_t)c * ktot + k] = (unsigned short)f2bf(W[t]);
    }
}

// ---------------- propagation: one wave per node, bf16 gathers ----------------
// xin/xout: packed 2xbf16 per uint, row = 64 uints (128 features). fp32 accumulate.

__global__ __launch_bounds__(256) void hop_bf_kernel(const int* __restrict__ offs,
                                                     const uint2* __restrict__ crw,
                                                     const unsigned int* __restrict__ xin,
                                                     unsigned int* __restrict__ xout, int n) {
    int wave = (blockIdx.x * 256 + threadIdx.x) >> 6;
    wave = __builtin_amdgcn_readfirstlane(wave);  // wave-uniform -> scalar CSR loads
    if (wave >= n) return;
    const int lane = threadIdx.x & 63;
    const int beg = offs[wave];
    const int end = offs[wave + 1];
    float ax = 0.f, ay = 0.f;
    int e = beg;
    for (; e + 4 <= end; e += 4) {
        uint2 e0 = crw[e], e1 = crw[e + 1], e2 = crw[e + 2], e3 = crw[e + 3];
        unsigned int v0 = xin[(size_t)e0.x * 64 + lane];
        unsigned int v1 = xin[(size_t)e1.x * 64 + lane];
        unsigned int v2 = xin[(size_t)e2.x * 64 + lane];
        unsigned int v3 = xin[(size_t)e3.x * 64 + lane];
        float w0 = __uint_as_float(e0.y), w1 = __uint_as_float(e1.y);
        float w2 = __uint_as_float(e2.y), w3 = __uint_as_float(e3.y);
        ax = fmaf(w0, __uint_as_float(v0 << 16), ax);
        ay = fmaf(w0, __uint_as_float(v0 & 0xFFFF0000u), ay);
        ax = fmaf(w1, __uint_as_float(v1 << 16), ax);
        ay = fmaf(w1, __uint_as_float(v1 & 0xFFFF0000u), ay);
        ax = fmaf(w2, __uint_as_float(v2 << 16), ax);
        ay = fmaf(w2, __uint_as_float(v2 & 0xFFFF0000u), ay);
        ax = fmaf(w3, __uint_as_float(v3 << 16), ax);
        ay = fmaf(w3, __uint_as_float(v3 & 0xFFFF0000u), ay);
    }
    for (; e < end; ++e) {
        uint2 er = crw[e];
        float w = __uint_as_float(er.y);
        unsigned int v = xin[(size_t)er.x * 64 + lane];
        ax = fmaf(w, __uint_as_float(v << 16), ax);
        ay = fmaf(w, __uint_as_float(v & 0xFFFF0000u), ay);
    }
    xout[(size_t)wave * 64 + lane] = f2bf(ax) | (f2bf(ay) << 16);
}

// ---------------- MFMA output GEMM ----------------
// out[n,128] = bf16([feature|xs]) @ bf16(W) + b.  Block: 64 rows x 128 cols, 4 waves.
// LDS tiles use 8-elem-block XOR swizzle (blk ^= row&7) to kill b128 bank conflicts.
__global__ __launch_bounds__(256) void gemm_mfma_kernel(const unsigned short* __restrict__ featbf,
                                                        const unsigned short* __restrict__ xsbf,
                                                        const unsigned short* __restrict__ WT,
                                                        const float* __restrict__ bvec,
                                                        float* __restrict__ out,
                                                        int n, int kk /* = K+1 */) {
    __shared__ unsigned short Abuf[64 * 64];
    __shared__ unsigned short Bbuf[128 * 64];
    const int tid = threadIdx.x;
    const int bm = blockIdx.x * 64;
    const int w = tid >> 6;
    const int lane = tid & 63;
    const int l15 = lane & 15;
    const int kgrp = lane >> 4;

    floatx4 acc[8];
#pragma unroll
    for (int f = 0; f < 8; ++f) {
        float bv = bvec[f * 16 + l15];
        acc[f] = (floatx4){bv, bv, bv, bv};
    }

    const int sa_row = tid >> 2;   // 0..63
    const int sa_b0 = tid & 3;     // A blocks sa_b0, sa_b0+4
    int ga_row = bm + sa_row;
    if (ga_row > n - 1) ga_row = n - 1;
    const int sb_row = tid >> 1;   // 0..127
    const int sb_b0 = tid & 1;     // B blocks +0,2,4,6

    const int KTOT = kk * 128;
    const int arow16 = w * 16 + l15;
    for (int kt = 0; kt < KTOT; kt += 64) {
        const int hop = kt >> 7;
        const int koff = kt & 127;
        const unsigned short* Abase = (hop == 0) ? featbf : (xsbf + (size_t)(hop - 1) * n * 128);
        const unsigned short* asrc = Abase + (size_t)ga_row * 128 + koff;
#pragma unroll
        for (int q = 0; q < 2; ++q) {
            int blk = sa_b0 + q * 4;
            short8 v = *(const short8*)(asrc + blk * 8);
            *(short8*)&Abuf[sa_row * 64 + ((blk ^ (sa_row & 7)) * 8)] = v;
        }
        const unsigned short* bsrc = WT + (size_t)sb_row * KTOT + kt;
#pragma unroll
        for (int q = 0; q < 4; ++q) {
            int blk = sb_b0 + q * 2;
            short8 v = *(const short8*)(bsrc + blk * 8);
            *(short8*)&Bbuf[sb_row * 64 + ((blk ^ (sb_row & 7)) * 8)] = v;
        }
        __syncthreads();
#pragma unroll
        for (int s = 0; s < 2; ++s) {
            int ablk = (s * 4 + kgrp) ^ (arow16 & 7);
            short8 a = *(const short8*)&Abuf[arow16 * 64 + ablk * 8];
#pragma unroll
            for (int f = 0; f < 8; ++f) {
                int c = f * 16 + l15;
                int bblk = (s * 4 + kgrp) ^ (c & 7);
                short8 b = *(const short8*)&Bbuf[c * 64 + bblk * 8];
                acc[f] = __builtin_amdgcn_mfma_f32_16x16x32_bf16(a, b, acc[f], 0, 0, 0);
            }
        }
        __syncthreads();
    }
    // C/D layout (HW-verified): row=(lane>>4)*4+reg, col=lane&15
#pragma unroll
    for (int f = 0; f < 8; ++f) {
        int ocol = f * 16 + l15;
#pragma unroll
        for (int r = 0; r < 4; ++r) {
            int orow = bm + w * 16 + kgrp * 4 + r;
            if (orow < n) out[(size_t)orow * 128 + ocol] = acc[f][r];
        }
    }
}

// ---- fallback (small ws): fp32 accumulating GEMM path ----

__global__ __launch_bounds__(256) void init_out_kernel(float* __restrict__ out,
                                                       const float* __restrict__ b, int total) {
    int t = blockIdx.x * 256 + threadIdx.x;
    if (t < total) out[t] = b[t & 127];
}

__global__ __launch_bounds__(256) void gemm_acc_kernel(const float* __restrict__ A,
                                                       const float* __restrict__ B,
                                                       float* __restrict__ C, int n) {
    __shared__ float As[64][32];
    __shared__ float Bs[32][128];
    const int tid = threadIdx.x;
    const int bm = blockIdx.x * 64;
    const int tc = tid & 31;
    const int tr = tid >> 5;

    float acc[8][4];
#pragma unroll
    for (int i = 0; i < 8; ++i)
#pragma unroll
        for (int c = 0; c < 4; ++c) acc[i][c] = 0.f;

    const int r0 = tid >> 2;
    const int c0 = (tid & 3) * 8;
    int arow = bm + r0;
    if (arow > n - 1) arow = n - 1;

    for (int jt = 0; jt < 128; jt += 32) {
        const float* src = A + (size_t)arow * 128 + jt + c0;
        float4 a0 = *(const float4*)(src);
        float4 a1 = *(const float4*)(src + 4);
        *(float4*)&As[r0][c0]     = a0;
        *(float4*)&As[r0][c0 + 4] = a1;
        const float4* bsrc = (const float4*)(B + jt * 128);
        float4* bdst = (float4*)Bs;
#pragma unroll
        for (int q = 0; q < 4; ++q) bdst[tid + q * 256] = bsrc[tid + q * 256];
        __syncthreads();
#pragma unroll
        for (int j4 = 0; j4 < 32; j4 += 4) {
            float4 w0 = *(const float4*)&Bs[j4 + 0][tc * 4];
            float4 w1 = *(const float4*)&Bs[j4 + 1][tc * 4];
            float4 w2 = *(const float4*)&Bs[j4 + 2][tc * 4];
            float4 w3 = *(const float4*)&Bs[j4 + 3][tc * 4];
#pragma unroll
            for (int i = 0; i < 8; ++i) {
                float4 av = *(const float4*)&As[tr * 8 + i][j4];
                acc[i][0] += av.x * w0.x + av.y * w1.x + av.z * w2.x + av.w * w3.x;
                acc[i][1] += av.x * w0.y + av.y * w1.y + av.z * w2.y + av.w * w3.y;
                acc[i][2] += av.x * w0.z + av.y * w1.z + av.z * w2.z + av.w * w3.z;
                acc[i][3] += av.x * w0.w + av.y * w1.w + av.z * w2.w + av.w * w3.w;
            }
        }
        __syncthreads();
    }
#pragma unroll
    for (int i = 0; i < 8; ++i) {
        int row = bm + tr * 8 + i;
        if (row < n) {
            float4* cp = (float4*)(C + (size_t)row * 128 + tc * 4);
            float4 cv = *cp;
            cv.x += acc[i][0]; cv.y += acc[i][1]; cv.z += acc[i][2]; cv.w += acc[i][3];
            *cp = cv;
        }
    }
}

__global__ __launch_bounds__(256) void hop_plain_kernel(const int* __restrict__ offs,
                                                        const uint2* __restrict__ crw,
                                                        const float* __restrict__ xin,
                                                        float* __restrict__ xout, int n) {
    int wave = (blockIdx.x * 256 + threadIdx.x) >> 6;
    wave = __builtin_amdgcn_readfirstlane(wave);
    if (wave >= n) return;
    const int lane = threadIdx.x & 63;
    const int beg = offs[wave];
    const int end = offs[wave + 1];
    const float2* __restrict__ x2 = (const float2*)xin;
    float ax = 0.f, ay = 0.f;
    for (int e = beg; e < end; ++e) {
        uint2 er = crw[e];
        float w = __uint_as_float(er.y);
        float2 v = x2[(size_t)er.x * 64 + lane];
        ax = fmaf(w, v.x, ax); ay = fmaf(w, v.y, ay);
    }
    float2 o; o.x = ax; o.y = ay;
    ((float2*)xout)[(size_t)wave * 64 + lane] = o;
}

// ---------------- launch ----------------

extern "C" void kernel_launch(void* const* d_in, const int* in_sizes, int n_in,
                              void* d_out, int out_size, void* d_ws, size_t ws_size,
                              hipStream_t stream) {
    const int D = 128;
    const int N = in_sizes[0] / D;
    const int E = in_sizes[1] / 2;
    const int K = in_sizes[2] / (D * D) - 1;  // 8
    const int KTOT = (K + 1) * D;             // 1152

    const float* feature = (const float*)d_in[0];
    const int*   ei      = (const int*)d_in[1];
    const float* W       = (const float*)d_in[2];
    const float* bvec    = (const float*)d_in[3];
    float* out = (float*)d_out;

    const int* row = ei;
    const int* col = ei + E;

    char* p = (char*)d_ws;
    auto alloc = [&](size_t bytes) {
        char* r = p;
        p += (bytes + 255) & ~(size_t)255;
        return r;
    };
    const int NB = (N + 255) / 256;
    unsigned int* deg = (unsigned int*)alloc((size_t)N * 4);
    float* dinv       = (float*)alloc((size_t)N * 4);
    int* offs         = (int*)alloc((size_t)(N + 1) * 4);
    int* cursor       = (int*)alloc((size_t)N * 4);
    int* bsum         = (int*)alloc((size_t)NB * 4);
    int* bpre         = (int*)alloc((size_t)NB * 4);
    uint2* crw        = (uint2*)alloc((size_t)(E + N) * 8);

    size_t used = (size_t)(p - (char*)d_ws);
    // mfma path: featbf + xsbf + WT
    size_t need_new = (size_t)N * D * 2 + (size_t)K * N * D * 2 + (size_t)KTOT * D * 2 + 8 * 4096;
    bool mfma_path = (ws_size - used) >= need_new;

    // graph build
    init_deg_kernel<<<(N + 255) / 256, 256, 0, stream>>>(deg, N);
    count_edges_kernel<<<(E + 255) / 256, 256, 0, stream>>>(col, deg, E);
    dinv_kernel<<<(N + 255) / 256, 256, 0, stream>>>(deg, dinv, N);
    block_sum_kernel<<<NB, 256, 0, stream>>>(deg, bsum, N);
    scan_sums_kernel<<<1, 1024, 0, stream>>>(bsum, bpre, offs + N, NB);
    block_scan_kernel<<<NB, 256, 0, stream>>>(deg, bpre, offs, cursor, N);
    fill_csr_kernel<<<(E + N + 255) / 256, 256, 0, stream>>>(row, col, dinv, cursor, crw, E, N);

    if (mfma_path) {
        unsigned int* featbf = (unsigned int*)alloc((size_t)N * D * 2);  // N*64 uints
        unsigned short* xsbf = (unsigned short*)alloc((size_t)K * N * D * 2);
        unsigned short* WT   = (unsigned short*)alloc((size_t)KTOT * D * 2);

        conv_feat_kernel<<<(N * 64 + 255) / 256, 256, 0, stream>>>((const float2*)feature, featbf, N * 64);
        transpose_w_kernel<<<(KTOT * D + 255) / 256, 256, 0, stream>>>(W, WT, KTOT);

        const unsigned int* xin = featbf;
        for (int k = 1; k <= K; ++k) {
            unsigned int* xo = (unsigned int*)(xsbf + (size_t)(k - 1) * N * D);
            hop_bf_kernel<<<(N * 64 + 255) / 256, 256, 0, stream>>>(offs, crw, xin, xo, N);
            xin = xo;
        }
        gemm_mfma_kernel<<<(N + 63) / 64, 256, 0, stream>>>(
            (const unsigned short*)featbf, xsbf, WT, bvec, out, N, K + 1);
    } else {
        float* xA = (float*)alloc((size_t)N * D * 4);
        float* xB = (float*)alloc((size_t)N * D * 4);
        init_out_kernel<<<(N * D + 255) / 256, 256, 0, stream>>>(out, bvec, N * D);
        gemm_acc_kernel<<<(N + 63) / 64, 256, 0, stream>>>(feature, W, out, N);
        const float* xin = feature;
        float* xout = xA;
        for (int k = 1; k <= K; ++k) {
            hop_plain_kernel<<<(N * 64 + 255) / 256, 256, 0, stream>>>(offs, crw, xin, xout, N);
            gemm_acc_kernel<<<(N + 63) / 64, 256, 0, stream>>>(xout, W + (size_t)k * D * D, out, N);
            xin = xout;
            xout = (xout == xA) ? xB : xA;
        }
    }
}

// Round 16
// 686.422 us; speedup vs baseline: 2.5782x; 1.0001x over previous
//
#include <hip/hip_runtime.h>
#include <hip/hip_bf16.h>

typedef short short8 __attribute__((ext_vector_type(8)));
typedef float floatx4 __attribute__((ext_vector_type(4)));

__device__ inline unsigned int f2bf(float f) {
    unsigned int u = __float_as_uint(f);
    return (u + 0x7FFFu + ((u >> 16) & 1u)) >> 16;  // round-to-nearest-even bf16
}

// ---------------- graph build ----------------

__global__ __launch_bounds__(256) void init_deg_kernel(unsigned int* __restrict__ deg, int n) {
    int i = blockIdx.x * 256 + threadIdx.x;
    if (i < n) deg[i] = 1u;  // self-loop
}

__global__ __launch_bounds__(256) void count_edges_kernel(const int* __restrict__ col,
                                                          unsigned int* __restrict__ deg, int E) {
    int e = blockIdx.x * 256 + threadIdx.x;
    if (e < E) atomicAdd(&deg[col[e]], 1u);
}

__global__ __launch_bounds__(256) void dinv_kernel(const unsigned int* __restrict__ deg,
                                                   float* __restrict__ dinv, int n) {
    int i = blockIdx.x * 256 + threadIdx.x;
    if (i < n) dinv[i] = 1.0f / sqrtf((float)deg[i]);
}

__global__ __launch_bounds__(256) void block_sum_kernel(const unsigned int* __restrict__ deg,
                                                        int* __restrict__ bsum, int n) {
    __shared__ int sm[256];
    int i = blockIdx.x * 256 + threadIdx.x;
    sm[threadIdx.x] = (i < n) ? (int)deg[i] : 0;
    __syncthreads();
    for (int off = 128; off > 0; off >>= 1) {
        if (threadIdx.x < off) sm[threadIdx.x] += sm[threadIdx.x + off];
        __syncthreads();
    }
    if (threadIdx.x == 0) bsum[blockIdx.x] = sm[0];
}

__global__ __launch_bounds__(1024) void scan_sums_kernel(const int* __restrict__ bsum,
                                                         int* __restrict__ bpre,
                                                         int* __restrict__ offs_n, int nb) {
    __shared__ int sm[1024];
    int t = threadIdx.x;
    sm[t] = (t < nb) ? bsum[t] : 0;
    __syncthreads();
    for (int off = 1; off < 1024; off <<= 1) {
        int v = (t >= off) ? sm[t - off] : 0;
        __syncthreads();
        sm[t] += v;
        __syncthreads();
    }
    if (t < nb) bpre[t] = (t == 0) ? 0 : sm[t - 1];
    if (t == 1023) offs_n[0] = sm[1023];
}

__global__ __launch_bounds__(256) void block_scan_kernel(const unsigned int* __restrict__ deg,
                                                         const int* __restrict__ bpre,
                                                         int* __restrict__ offs,
                                                         int* __restrict__ cursor, int n) {
    __shared__ int sm[256];
    int t = threadIdx.x;
    int i = blockIdx.x * 256 + t;
    int v = (i < n) ? (int)deg[i] : 0;
    sm[t] = v;
    __syncthreads();
    for (int off = 1; off < 256; off <<= 1) {
        int u = (t >= off) ? sm[t - off] : 0;
        __syncthreads();
        sm[t] += u;
        __syncthreads();
    }
    if (i < n) {
        int ex = bpre[blockIdx.x] + sm[t] - v;
        offs[i] = ex;
        cursor[i] = ex;
    }
}

// packed CSR record: .x = source row, .y = weight bits  (single 8B scatter store)
__global__ __launch_bounds__(256) void fill_csr_kernel(const int* __restrict__ row,
                                                       const int* __restrict__ col,
                                                       const float* __restrict__ dinv,
                                                       int* __restrict__ cursor,
                                                       uint2* __restrict__ crw,
                                                       int E, int n) {
    int t = blockIdx.x * 256 + threadIdx.x;
    if (t < E) {
        int r = row[t], c = col[t];
        int pos = atomicAdd(&cursor[c], 1);
        uint2 rec;
        rec.x = (unsigned int)r;
        rec.y = __float_as_uint(dinv[r] * dinv[c]);
        crw[pos] = rec;
    } else if (t < E + n) {
        int i = t - E;
        int pos = atomicAdd(&cursor[i], 1);
        float d = dinv[i];
        uint2 rec;
        rec.x = (unsigned int)i;
        rec.y = __float_as_uint(d * d);
        crw[pos] = rec;
    }
}

// ---------------- one-time converts ----------------

__global__ __launch_bounds__(256) void conv_feat_kernel(const float2* __restrict__ src,
                                                        unsigned int* __restrict__ dst, int total) {
    int i = blockIdx.x * 256 + threadIdx.x;
    if (i < total) {
        float2 v = src[i];
        dst[i] = f2bf(v.x) | (f2bf(v.y) << 16);
    }
}

// WT[c][k] = bf16(W[k][c]); WT is [128][KTOT]
__global__ __launch_bounds__(256) void transpose_w_kernel(const float* __restrict__ W,
                                                          unsigned short* __restrict__ WT,
                                                          int ktot) {
    int t = blockIdx.x * 256 + threadIdx.x;
    if (t < ktot * 128) {
        int k = t >> 7, c = t & 127;
        WT[(size_t)c * ktot + k] = (unsigned short)f2bf(W[t]);
    }
}

// ---------------- propagation: one wave per node, 2 edges per gather instr ----------------
// xin/xout: packed 2xbf16 per uint, row = 32 uint2 (128 features). fp32 accumulate.
// Half-wave h (lanes 32h..32h+31) handles edge e+h; each lane loads uint2 = 4 features.
// Cross-half __shfl reduction at the end; lanes 0-31 write the packed row.

__global__ __launch_bounds__(256) void hop_bf2_kernel(const int* __restrict__ offs,
                                                      const uint2* __restrict__ crw,
                                                      const uint2* __restrict__ xin2,
                                                      uint2* __restrict__ xout2, int n) {
    int wave = (blockIdx.x * 256 + threadIdx.x) >> 6;
    wave = __builtin_amdgcn_readfirstlane(wave);  // wave-uniform -> scalar CSR loads
    if (wave >= n) return;
    const int lane = threadIdx.x & 63;
    const int half = lane >> 5;    // 0 or 1: which edge of the pair
    const int off = lane & 31;     // uint2 index within row (features 4*off .. 4*off+3)
    const int beg = offs[wave];
    const int end = offs[wave + 1];
    float a0 = 0.f, a1 = 0.f, a2 = 0.f, a3 = 0.f;
    int e = beg;
    for (; e + 4 <= end; e += 4) {
        uint2 eA0 = crw[e],     eB0 = crw[e + 1];
        uint2 eA1 = crw[e + 2], eB1 = crw[e + 3];
        unsigned int r0 = half ? eB0.x : eA0.x;
        unsigned int r1 = half ? eB1.x : eA1.x;
        float w0 = __uint_as_float(half ? eB0.y : eA0.y);
        float w1 = __uint_as_float(half ? eB1.y : eA1.y);
        uint2 v0 = xin2[(size_t)r0 * 32 + off];
        uint2 v1 = xin2[(size_t)r1 * 32 + off];
        a0 = fmaf(w0, __uint_as_float(v0.x << 16), a0);
        a1 = fmaf(w0, __uint_as_float(v0.x & 0xFFFF0000u), a1);
        a2 = fmaf(w0, __uint_as_float(v0.y << 16), a2);
        a3 = fmaf(w0, __uint_as_float(v0.y & 0xFFFF0000u), a3);
        a0 = fmaf(w1, __uint_as_float(v1.x << 16), a0);
        a1 = fmaf(w1, __uint_as_float(v1.x & 0xFFFF0000u), a1);
        a2 = fmaf(w1, __uint_as_float(v1.y << 16), a2);
        a3 = fmaf(w1, __uint_as_float(v1.y & 0xFFFF0000u), a3);
    }
    for (; e + 2 <= end; e += 2) {
        uint2 eA = crw[e], eB = crw[e + 1];
        unsigned int r = half ? eB.x : eA.x;
        float w = __uint_as_float(half ? eB.y : eA.y);
        uint2 v = xin2[(size_t)r * 32 + off];
        a0 = fmaf(w, __uint_as_float(v.x << 16), a0);
        a1 = fmaf(w, __uint_as_float(v.x & 0xFFFF0000u), a1);
        a2 = fmaf(w, __uint_as_float(v.y << 16), a2);
        a3 = fmaf(w, __uint_as_float(v.y & 0xFFFF0000u), a3);
    }
    if (e < end) {  // odd tail: both halves gather same row, half 1 uses w=0
        uint2 eA = crw[e];
        float w = half ? 0.f : __uint_as_float(eA.y);
        uint2 v = xin2[(size_t)eA.x * 32 + off];
        a0 = fmaf(w, __uint_as_float(v.x << 16), a0);
        a1 = fmaf(w, __uint_as_float(v.x & 0xFFFF0000u), a1);
        a2 = fmaf(w, __uint_as_float(v.y << 16), a2);
        a3 = fmaf(w, __uint_as_float(v.y & 0xFFFF0000u), a3);
    }
    // combine the two half-wave partial sums (lane l <-> lane l^32)
    a0 += __shfl(a0, lane ^ 32, 64);
    a1 += __shfl(a1, lane ^ 32, 64);
    a2 += __shfl(a2, lane ^ 32, 64);
    a3 += __shfl(a3, lane ^ 32, 64);
    if (half == 0) {
        uint2 o;
        o.x = f2bf(a0) | (f2bf(a1) << 16);
        o.y = f2bf(a2) | (f2bf(a3) << 16);
        xout2[(size_t)wave * 32 + off] = o;
    }
}

// ---------------- MFMA output GEMM ----------------
// out[n,128] = bf16([feature|xs]) @ bf16(W) + b.  Block: 64 rows x 128 cols, 4 waves.
// LDS tiles use 8-elem-block XOR swizzle (blk ^= row&7) to kill b128 bank conflicts.
__global__ __launch_bounds__(256) void gemm_mfma_kernel(const unsigned short* __restrict__ featbf,
                                                        const unsigned short* __restrict__ xsbf,
                                                        const unsigned short* __restrict__ WT,
                                                        const float* __restrict__ bvec,
                                                        float* __restrict__ out,
                                                        int n, int kk /* = K+1 */) {
    __shared__ unsigned short Abuf[64 * 64];
    __shared__ unsigned short Bbuf[128 * 64];
    const int tid = threadIdx.x;
    const int bm = blockIdx.x * 64;
    const int w = tid >> 6;
    const int lane = tid & 63;
    const int l15 = lane & 15;
    const int kgrp = lane >> 4;

    floatx4 acc[8];
#pragma unroll
    for (int f = 0; f < 8; ++f) {
        float bv = bvec[f * 16 + l15];
        acc[f] = (floatx4){bv, bv, bv, bv};
    }

    const int sa_row = tid >> 2;   // 0..63
    const int sa_b0 = tid & 3;     // A blocks sa_b0, sa_b0+4
    int ga_row = bm + sa_row;
    if (ga_row > n - 1) ga_row = n - 1;
    const int sb_row = tid >> 1;   // 0..127
    const int sb_b0 = tid & 1;     // B blocks +0,2,4,6

    const int KTOT = kk * 128;
    const int arow16 = w * 16 + l15;
    for (int kt = 0; kt < KTOT; kt += 64) {
        const int hop = kt >> 7;
        const int koff = kt & 127;
        const unsigned short* Abase = (hop == 0) ? featbf : (xsbf + (size_t)(hop - 1) * n * 128);
        const unsigned short* asrc = Abase + (size_t)ga_row * 128 + koff;
#pragma unroll
        for (int q = 0; q < 2; ++q) {
            int blk = sa_b0 + q * 4;
            short8 v = *(const short8*)(asrc + blk * 8);
            *(short8*)&Abuf[sa_row * 64 + ((blk ^ (sa_row & 7)) * 8)] = v;
        }
        const unsigned short* bsrc = WT + (size_t)sb_row * KTOT + kt;
#pragma unroll
        for (int q = 0; q < 4; ++q) {
            int blk = sb_b0 + q * 2;
            short8 v = *(const short8*)(bsrc + blk * 8);
            *(short8*)&Bbuf[sb_row * 64 + ((blk ^ (sb_row & 7)) * 8)] = v;
        }
        __syncthreads();
#pragma unroll
        for (int s = 0; s < 2; ++s) {
            int ablk = (s * 4 + kgrp) ^ (arow16 & 7);
            short8 a = *(const short8*)&Abuf[arow16 * 64 + ablk * 8];
#pragma unroll
            for (int f = 0; f < 8; ++f) {
                int c = f * 16 + l15;
                int bblk = (s * 4 + kgrp) ^ (c & 7);
                short8 b = *(const short8*)&Bbuf[c * 64 + bblk * 8];
                acc[f] = __builtin_amdgcn_mfma_f32_16x16x32_bf16(a, b, acc[f], 0, 0, 0);
            }
        }
        __syncthreads();
    }
    // C/D layout (HW-verified): row=(lane>>4)*4+reg, col=lane&15
#pragma unroll
    for (int f = 0; f < 8; ++f) {
        int ocol = f * 16 + l15;
#pragma unroll
        for (int r = 0; r < 4; ++r) {
            int orow = bm + w * 16 + kgrp * 4 + r;
            if (orow < n) out[(size_t)orow * 128 + ocol] = acc[f][r];
        }
    }
}

// ---- fallback (small ws): fp32 accumulating GEMM path ----

__global__ __launch_bounds__(256) void init_out_kernel(float* __restrict__ out,
                                                       const float* __restrict__ b, int total) {
    int t = blockIdx.x * 256 + threadIdx.x;
    if (t < total) out[t] = b[t & 127];
}

__global__ __launch_bounds__(256) void gemm_acc_kernel(const float* __restrict__ A,
                                                       const float* __restrict__ B,
                                                       float* __restrict__ C, int n) {
    __shared__ float As[64][32];
    __shared__ float Bs[32][128];
    const int tid = threadIdx.x;
    const int bm = blockIdx.x * 64;
    const int tc = tid & 31;
    const int tr = tid >> 5;

    float acc[8][4];
#pragma unroll
    for (int i = 0; i < 8; ++i)
#pragma unroll
        for (int c = 0; c < 4; ++c) acc[i][c] = 0.f;

    const int r0 = tid >> 2;
    const int c0 = (tid & 3) * 8;
    int arow = bm + r0;
    if (arow > n - 1) arow = n - 1;

    for (int jt = 0; jt < 128; jt += 32) {
        const float* src = A + (size_t)arow * 128 + jt + c0;
        float4 a0 = *(const float4*)(src);
        float4 a1 = *(const float4*)(src + 4);
        *(float4*)&As[r0][c0]     = a0;
        *(float4*)&As[r0][c0 + 4] = a1;
        const float4* bsrc = (const float4*)(B + jt * 128);
        float4* bdst = (float4*)Bs;
#pragma unroll
        for (int q = 0; q < 4; ++q) bdst[tid + q * 256] = bsrc[tid + q * 256];
        __syncthreads();
#pragma unroll
        for (int j4 = 0; j4 < 32; j4 += 4) {
            float4 w0 = *(const float4*)&Bs[j4 + 0][tc * 4];
            float4 w1 = *(const float4*)&Bs[j4 + 1][tc * 4];
            float4 w2 = *(const float4*)&Bs[j4 + 2][tc * 4];
            float4 w3 = *(const float4*)&Bs[j4 + 3][tc * 4];
#pragma unroll
            for (int i = 0; i < 8; ++i) {
                float4 av = *(const float4*)&As[tr * 8 + i][j4];
                acc[i][0] += av.x * w0.x + av.y * w1.x + av.z * w2.x + av.w * w3.x;
                acc[i][1] += av.x * w0.y + av.y * w1.y + av.z * w2.y + av.w * w3.y;
                acc[i][2] += av.x * w0.z + av.y * w1.z + av.z * w2.z + av.w * w3.z;
                acc[i][3] += av.x * w0.w + av.y * w1.w + av.z * w2.w + av.w * w3.w;
            }
        }
        __syncthreads();
    }
#pragma unroll
    for (int i = 0; i < 8; ++i) {
        int row = bm + tr * 8 + i;
        if (row < n) {
            float4* cp = (float4*)(C + (size_t)row * 128 + tc * 4);
            float4 cv = *cp;
            cv.x += acc[i][0]; cv.y += acc[i][1]; cv.z += acc[i][2]; cv.w += acc[i][3];
            *cp = cv;
        }
    }
}

__global__ __launch_bounds__(256) void hop_plain_kernel(const int* __restrict__ offs,
                                                        const uint2* __restrict__ crw,
                                                        const float* __restrict__ xin,
                                                        float* __restrict__ xout, int n) {
    int wave = (blockIdx.x * 256 + threadIdx.x) >> 6;
    wave = __builtin_amdgcn_readfirstlane(wave);
    if (wave >= n) return;
    const int lane = threadIdx.x & 63;
    const int beg = offs[wave];
    const int end = offs[wave + 1];
    const float2* __restrict__ x2 = (const float2*)xin;
    float ax = 0.f, ay = 0.f;
    for (int e = beg; e < end; ++e) {
        uint2 er = crw[e];
        float w = __uint_as_float(er.y);
        float2 v = x2[(size_t)er.x * 64 + lane];
        ax = fmaf(w, v.x, ax); ay = fmaf(w, v.y, ay);
    }
    float2 o; o.x = ax; o.y = ay;
    ((float2*)xout)[(size_t)wave * 64 + lane] = o;
}

// ---------------- launch ----------------

extern "C" void kernel_launch(void* const* d_in, const int* in_sizes, int n_in,
                              void* d_out, int out_size, void* d_ws, size_t ws_size,
                              hipStream_t stream) {
    const int D = 128;
    const int N = in_sizes[0] / D;
    const int E = in_sizes[1] / 2;
    const int K = in_sizes[2] / (D * D) - 1;  // 8
    const int KTOT = (K + 1) * D;             // 1152

    const float* feature = (const float*)d_in[0];
    const int*   ei      = (const int*)d_in[1];
    const float* W       = (const float*)d_in[2];
    const float* bvec    = (const float*)d_in[3];
    float* out = (float*)d_out;

    const int* row = ei;
    const int* col = ei + E;

    char* p = (char*)d_ws;
    auto alloc = [&](size_t bytes) {
        char* r = p;
        p += (bytes + 255) & ~(size_t)255;
        return r;
    };
    const int NB = (N + 255) / 256;
    unsigned int* deg = (unsigned int*)alloc((size_t)N * 4);
    float* dinv       = (float*)alloc((size_t)N * 4);
    int* offs         = (int*)alloc((size_t)(N + 1) * 4);
    int* cursor       = (int*)alloc((size_t)N * 4);
    int* bsum         = (int*)alloc((size_t)NB * 4);
    int* bpre         = (int*)alloc((size_t)NB * 4);
    uint2* crw        = (uint2*)alloc((size_t)(E + N) * 8);

    size_t used = (size_t)(p - (char*)d_ws);
    // mfma path: featbf + xsbf + WT
    size_t need_new = (size_t)N * D * 2 + (size_t)K * N * D * 2 + (size_t)KTOT * D * 2 + 8 * 4096;
    bool mfma_path = (ws_size - used) >= need_new;

    // graph build
    init_deg_kernel<<<(N + 255) / 256, 256, 0, stream>>>(deg, N);
    count_edges_kernel<<<(E + 255) / 256, 256, 0, stream>>>(col, deg, E);
    dinv_kernel<<<(N + 255) / 256, 256, 0, stream>>>(deg, dinv, N);
    block_sum_kernel<<<NB, 256, 0, stream>>>(deg, bsum, N);
    scan_sums_kernel<<<1, 1024, 0, stream>>>(bsum, bpre, offs + N, NB);
    block_scan_kernel<<<NB, 256, 0, stream>>>(deg, bpre, offs, cursor, N);
    fill_csr_kernel<<<(E + N + 255) / 256, 256, 0, stream>>>(row, col, dinv, cursor, crw, E, N);

    if (mfma_path) {
        unsigned int* featbf = (unsigned int*)alloc((size_t)N * D * 2);  // N*64 uints
        unsigned short* xsbf = (unsigned short*)alloc((size_t)K * N * D * 2);
        unsigned short* WT   = (unsigned short*)alloc((size_t)KTOT * D * 2);

        conv_feat_kernel<<<(N * 64 + 255) / 256, 256, 0, stream>>>((const float2*)feature, featbf, N * 64);
        transpose_w_kernel<<<(KTOT * D + 255) / 256, 256, 0, stream>>>(W, WT, KTOT);

        const uint2* xin2 = (const uint2*)featbf;
        for (int k = 1; k <= K; ++k) {
            uint2* xo2 = (uint2*)(xsbf + (size_t)(k - 1) * N * D);
            hop_bf2_kernel<<<(N * 64 + 255) / 256, 256, 0, stream>>>(offs, crw, xin2, xo2, N);
            xin2 = xo2;
        }
        gemm_mfma_kernel<<<(N + 63) / 64, 256, 0, stream>>>(
            (const unsigned short*)featbf, xsbf, WT, bvec, out, N, K + 1);
    } else {
        float* xA = (float*)alloc((size_t)N * D * 4);
        float* xB = (float*)alloc((size_t)N * D * 4);
        init_out_kernel<<<(N * D + 255) / 256, 256, 0, stream>>>(out, bvec, N * D);
        gemm_acc_kernel<<<(N + 63) / 64, 256, 0, stream>>>(feature, W, out, N);
        const float* xin = feature;
        float* xout = xA;
        for (int k = 1; k <= K; ++k) {
            hop_plain_kernel<<<(N * 64 + 255) / 256, 256, 0, stream>>>(offs, crw, xin, xout, N);
            gemm_acc_kernel<<<(N + 63) / 64, 256, 0, stream>>>(xout, W + (size_t)k * D * D, out, N);
            xin = xout;
            xout = (xout == xA) ? xB : xA;
        }
    }
}